// Round 3
// baseline (1839.220 us; speedup 1.0000x reference)
//
#include <hip/hip_runtime.h>
#include <hip/hip_bf16.h>
#include <cstdint>
#include <cstddef>

#define TK 8192
#define DIM 1024
#define HID 4096
#define NE 8

#define BM 128
#define BN 128
#define BK 32

typedef __attribute__((ext_vector_type(8))) __bf16 bfrag;   // 8 bf16 = 4 VGPR (MFMA A/B operand)
typedef __attribute__((ext_vector_type(4))) float ffrag;    // MFMA C/D operand

static __device__ __forceinline__ ushort f2bf(float f) {
    union { float f; uint32_t u; } v; v.f = f;
    uint32_t r = (v.u + 0x7fffu + ((v.u >> 16) & 1u)) >> 16;   // RNE, finite inputs only
    return (ushort)r;
}

static __device__ __forceinline__ uint4 pack8(float4 a, float4 b) {
    union { ushort u[8]; uint4 q; } pk;
    pk.u[0] = f2bf(a.x); pk.u[1] = f2bf(a.y); pk.u[2] = f2bf(a.z); pk.u[3] = f2bf(a.w);
    pk.u[4] = f2bf(b.x); pk.u[5] = f2bf(b.y); pk.u[6] = f2bf(b.z); pk.u[7] = f2bf(b.w);
    return pk.q;
}

// async global->LDS, 16B per lane; LDS dest = wave-uniform base + lane*16 (m97/m104 semantics)
static __device__ __forceinline__ void gld16(const ushort* g, ushort* l) {
    __builtin_amdgcn_global_load_lds(
        (const __attribute__((address_space(1))) unsigned int*)g,
        (__attribute__((address_space(3))) unsigned int*)l, 16, 0, 0);
}

// LDS tile [128 rows][32 bf16], stored as superblocks of 8 rows x 4 chunks(16B):
//   chunk (r,kc) lives at slot (r>>3)*32 + kc*8 + (r&7)   (16B slots, =*8 ushorts)
// Read side: 16 lanes at fixed kc hit 8 distinct 16B bank-groups (2-way, free).
// Write side (gld16, linear slots s): r = (s>>5)*8 + (s&7), kc = (s>>3)&3.
#define LDSIDX(r, kc) ((((r) >> 3) << 8) + ((kc) << 6) + (((r) & 7) << 3))
#define SLOT_R(s) ((((s) >> 5) << 3) | ((s) & 7))
#define SLOT_KC(s) (((s) >> 3) & 3)

// ---------------- f32 -> bf16 streaming convert (8 elems/thread) ----------------
__global__ __launch_bounds__(256) void k_cvt(const float* __restrict__ src,
                                             ushort* __restrict__ dst, int n8) {
    int i = blockIdx.x * blockDim.x + threadIdx.x;
    if (i >= n8) return;
    const float4* p = (const float4*)src + (size_t)i * 2;
    ((uint4*)dst)[i] = pack8(p[0], p[1]);
}

// ---------------- router: f64-accurate logits, top-2, renormalized weights ----------------
__global__ __launch_bounds__(256) void k_router(const float* __restrict__ x,
                                                const float* __restrict__ gw,
                                                int* __restrict__ topi, float* __restrict__ topw) {
    int t = blockIdx.x * 4 + (threadIdx.x >> 6);
    int lane = threadIdx.x & 63;
    if (t >= TK) return;
    double acc[NE];
#pragma unroll
    for (int e = 0; e < NE; ++e) acc[e] = 0.0;
    const float* xr = x + (size_t)t * DIM;
    for (int k = lane; k < DIM; k += 64) {
        double xv = (double)xr[k];
#pragma unroll
        for (int e = 0; e < NE; ++e) acc[e] += xv * (double)gw[e * DIM + k];
    }
#pragma unroll
    for (int e = 0; e < NE; ++e) {
#pragma unroll
        for (int off = 32; off > 0; off >>= 1) acc[e] += __shfl_xor(acc[e], off);
    }
    if (lane == 0) {
        int i1 = 0;
#pragma unroll
        for (int e = 1; e < NE; ++e) if (acc[e] > acc[i1]) i1 = e;
        int i2 = (i1 == 0) ? 1 : 0;
#pragma unroll
        for (int e = 0; e < NE; ++e) if (e != i1 && acc[e] > acc[i2]) i2 = e;
        double w = 1.0 / (1.0 + exp(acc[i2] - acc[i1]));   // = p1/(p1+p2), Z cancels
        topi[t * 2 + 0] = i1; topi[t * 2 + 1] = i2;
        topw[t * 2 + 0] = (float)w; topw[t * 2 + 1] = (float)(1.0 - w);
    }
}

__global__ void k_count(const int* __restrict__ topi, int* __restrict__ counts) {
    int i = blockIdx.x * blockDim.x + threadIdx.x;
    if (i < 2 * TK) atomicAdd(&counts[topi[i]], 1);
}

__global__ void k_scan(const int* __restrict__ counts, int* __restrict__ offs, int* __restrict__ cursor) {
    if (threadIdx.x == 0 && blockIdx.x == 0) {
        int s = 0;
        for (int e = 0; e < NE; ++e) { offs[e] = s; cursor[e] = s; s += counts[e]; }
        offs[NE] = s;
    }
}

__global__ void k_scatter(const int* __restrict__ topi, const float* __restrict__ topw,
                          int* __restrict__ cursor, int* __restrict__ perm, float* __restrict__ pw) {
    int t = blockIdx.x * blockDim.x + threadIdx.x;
    if (t >= TK) return;
#pragma unroll
    for (int k = 0; k < 2; ++k) {
        int e = topi[t * 2 + k];
        int pos = atomicAdd(&cursor[e], 1);
        perm[pos] = t; pw[pos] = topw[t * 2 + k];
    }
}

// ---------------- GEMM A: H[pos,n] = silu(x@w1^T) * (x@w3^T), bf16 out ----------------
// Double-buffered: STAGE(next) -> COMPUTE(cur) -> one barrier per K-step (T3-min recipe).
template <bool PRE>
__global__ __launch_bounds__(256) void k_ffn1(const float* __restrict__ xf,
                                              const float* __restrict__ w1f,
                                              const float* __restrict__ w3f,
                                              const ushort* __restrict__ xb,
                                              const ushort* __restrict__ w1b,
                                              const ushort* __restrict__ w3b,
                                              const int* __restrict__ offs,
                                              const int* __restrict__ perm,
                                              ushort* __restrict__ H) {
    const int mt = blockIdx.x, nt = blockIdx.y, e = blockIdx.z;
    const int off = offs[e], end = offs[e + 1];
    const int m0 = off + mt * BM;
    if (m0 >= end) return;
    const int nrows = min(BM, end - m0);

    __shared__ ushort lA[2][BM * BK];
    __shared__ ushort lB1[2][BN * BK];
    __shared__ ushort lB3[2][BN * BK];
    __shared__ int lTok[BM];

    const int tid = threadIdx.x;
    if (tid < BM) lTok[tid] = (tid < nrows) ? perm[m0 + tid] : -1;
    __syncthreads();

    const int lane = tid & 63, wid = tid >> 6;
    const int wm = (wid >> 1) * 64, wn = (wid & 1) * 64;

    ffrag acc1[4][4], acc3[4][4];
#pragma unroll
    for (int i = 0; i < 4; ++i)
#pragma unroll
        for (int j = 0; j < 4; ++j) { acc1[i][j] = (ffrag)0.f; acc3[i][j] = (ffrag)0.f; }

    // per-lane source pointers, slot s = i*256 + tid  (2 slots/thread, 512 16B-chunks/tile)
    const ushort* pA[2]; const ushort* pB1[2]; const ushort* pB3[2];
    const float* fA[2]; const float* fB1[2]; const float* fB3[2];
    bool fAvalid[2];
    {
        const size_t wbase = (size_t)e * HID * DIM + (size_t)nt * BN * DIM;
#pragma unroll
        for (int i = 0; i < 2; ++i) {
            int s = i * 256 + tid;
            int r = SLOT_R(s), kc = SLOT_KC(s);
            int tok = lTok[r];
            if constexpr (PRE) {
                int tk = (tok < 0) ? 0 : tok;      // pad rows: finite garbage, discarded at store
                pA[i]  = xb + (size_t)tk * DIM + kc * 8;
                pB1[i] = w1b + wbase + (size_t)r * DIM + kc * 8;
                pB3[i] = w3b + wbase + (size_t)r * DIM + kc * 8;
            } else {
                fAvalid[i] = tok >= 0;
                fA[i]  = xf + (size_t)((tok < 0) ? 0 : tok) * DIM + kc * 8;
                fB1[i] = w1f + wbase + (size_t)r * DIM + kc * 8;
                fB3[i] = w3f + wbase + (size_t)r * DIM + kc * 8;
            }
        }
    }

#define STAGE1(buf, k0)                                                          \
    do {                                                                         \
        if constexpr (PRE) {                                                     \
            _Pragma("unroll")                                                    \
            for (int i = 0; i < 2; ++i) {                                        \
                const int ldso = (i * 256 + wid * 64) * 8;                       \
                gld16(pA[i] + (k0), &lA[buf][ldso]);                             \
                gld16(pB1[i] + (k0), &lB1[buf][ldso]);                           \
                gld16(pB3[i] + (k0), &lB3[buf][ldso]);                           \
            }                                                                    \
        } else {                                                                 \
            _Pragma("unroll")                                                    \
            for (int i = 0; i < 2; ++i) {                                        \
                int s = i * 256 + tid;                                           \
                int dst = s << 3;                                                \
                float4 z = make_float4(0.f, 0.f, 0.f, 0.f);                      \
                float4 a0 = z, a1 = z;                                           \
                if (fAvalid[i]) { a0 = *(const float4*)(fA[i] + (k0));           \
                                  a1 = *(const float4*)(fA[i] + (k0) + 4); }     \
                *(uint4*)&lA[buf][dst] = pack8(a0, a1);                          \
                *(uint4*)&lB1[buf][dst] = pack8(*(const float4*)(fB1[i] + (k0)), \
                                                *(const float4*)(fB1[i] + (k0) + 4)); \
                *(uint4*)&lB3[buf][dst] = pack8(*(const float4*)(fB3[i] + (k0)), \
                                                *(const float4*)(fB3[i] + (k0) + 4)); \
            }                                                                    \
        }                                                                        \
    } while (0)

    STAGE1(0, 0);
    __syncthreads();

    const int NT = DIM / BK;   // 32
    int cur = 0;
    for (int t = 0; t < NT; ++t) {
        if (t + 1 < NT) STAGE1(cur ^ 1, (t + 1) * BK);
        // compute on buf cur
        {
            bfrag a[4], b1[4], b3[4];
            const int kc = lane >> 4;
#pragma unroll
            for (int i = 0; i < 4; ++i) {
                int r = wm + i * 16 + (lane & 15);
                a[i] = *(const bfrag*)&lA[cur][LDSIDX(r, kc)];
            }
#pragma unroll
            for (int j = 0; j < 4; ++j) {
                int r = wn + j * 16 + (lane & 15);
                b1[j] = *(const bfrag*)&lB1[cur][LDSIDX(r, kc)];
                b3[j] = *(const bfrag*)&lB3[cur][LDSIDX(r, kc)];
            }
#pragma unroll
            for (int i = 0; i < 4; ++i)
#pragma unroll
                for (int j = 0; j < 4; ++j) {
                    acc1[i][j] = __builtin_amdgcn_mfma_f32_16x16x32_bf16(a[i], b1[j], acc1[i][j], 0, 0, 0);
                    acc3[i][j] = __builtin_amdgcn_mfma_f32_16x16x32_bf16(a[i], b3[j], acc3[i][j], 0, 0, 0);
                }
        }
        __syncthreads();   // drains vmcnt (next tile staged) + lgkm (our ds_reads)
        cur ^= 1;
    }
#undef STAGE1

    // epilogue: silu(h1)*h3 -> bf16 H.  C/D layout: col = lane&15, row = (lane>>4)*4 + q
    const int colbase = nt * BN + wn;
#pragma unroll
    for (int i = 0; i < 4; ++i) {
        int rbase = wm + i * 16 + ((lane >> 4) << 2);
#pragma unroll
        for (int q = 0; q < 4; ++q) {
            int rl = rbase + q;
            if (rl >= nrows) continue;
            size_t rowoff = (size_t)(m0 + rl) * HID;
#pragma unroll
            for (int j = 0; j < 4; ++j) {
                int col = colbase + j * 16 + (lane & 15);
                float h1 = acc1[i][j][q], h3 = acc3[i][j][q];
                float val = (h1 / (1.f + __expf(-h1))) * h3;
                H[rowoff + col] = f2bf(val);
            }
        }
    }
}

// ---------------- GEMM B: out[tok,:] += pw[pos] * (H[pos,:] @ w2^T) ----------------
template <bool PRE>
__global__ __launch_bounds__(256) void k_ffn2(const ushort* __restrict__ H,
                                              const float* __restrict__ w2f,
                                              const ushort* __restrict__ w2b,
                                              const int* __restrict__ offs,
                                              const int* __restrict__ perm,
                                              const float* __restrict__ pw,
                                              float* __restrict__ out) {
    const int mt = blockIdx.x, nt = blockIdx.y, e = blockIdx.z;
    const int off = offs[e], end = offs[e + 1];
    const int m0 = off + mt * BM;
    if (m0 >= end) return;
    const int nrows = min(BM, end - m0);

    __shared__ ushort lA[2][BM * BK];
    __shared__ ushort lB[2][BN * BK];
    __shared__ int lTok[BM];
    __shared__ float lPw[BM];

    const int tid = threadIdx.x;
    if (tid < BM) {
        bool v = tid < nrows;
        lTok[tid] = v ? perm[m0 + tid] : -1;
        lPw[tid]  = v ? pw[m0 + tid] : 0.f;
    }
    __syncthreads();

    const int lane = tid & 63, wid = tid >> 6;
    const int wm = (wid >> 1) * 64, wn = (wid & 1) * 64;

    ffrag acc[4][4];
#pragma unroll
    for (int i = 0; i < 4; ++i)
#pragma unroll
        for (int j = 0; j < 4; ++j) acc[i][j] = (ffrag)0.f;

    const ushort* pA[2]; const ushort* pB[2];
    const float* fB[2];
    {
        const size_t wbase = (size_t)e * DIM * HID + (size_t)nt * BN * HID;
#pragma unroll
        for (int i = 0; i < 2; ++i) {
            int s = i * 256 + tid;
            int r = SLOT_R(s), kc = SLOT_KC(s);
            int pos = m0 + r; if (pos > 2 * TK - 1) pos = 2 * TK - 1;   // clamp into H
            pA[i] = H + (size_t)pos * HID + kc * 8;
            if constexpr (PRE) pB[i] = w2b + wbase + (size_t)r * HID + kc * 8;
            else               fB[i] = w2f + wbase + (size_t)r * HID + kc * 8;
        }
    }

#define STAGE2(buf, k0)                                                          \
    do {                                                                         \
        if constexpr (PRE) {                                                     \
            _Pragma("unroll")                                                    \
            for (int i = 0; i < 2; ++i) {                                        \
                const int ldso = (i * 256 + wid * 64) * 8;                       \
                gld16(pA[i] + (k0), &lA[buf][ldso]);                             \
                gld16(pB[i] + (k0), &lB[buf][ldso]);                             \
            }                                                                    \
        } else {                                                                 \
            _Pragma("unroll")                                                    \
            for (int i = 0; i < 2; ++i) {                                        \
                int s = i * 256 + tid;                                           \
                int dst = s << 3;                                                \
                *(uint4*)&lA[buf][dst] = *(const uint4*)(pA[i] + (k0));          \
                *(uint4*)&lB[buf][dst] = pack8(*(const float4*)(fB[i] + (k0)),   \
                                               *(const float4*)(fB[i] + (k0) + 4)); \
            }                                                                    \
        }                                                                        \
    } while (0)

    STAGE2(0, 0);
    __syncthreads();

    const int NT = HID / BK;   // 128
    int cur = 0;
    for (int t = 0; t < NT; ++t) {
        if (t + 1 < NT) STAGE2(cur ^ 1, (t + 1) * BK);
        {
            bfrag a[4], b[4];
            const int kc = lane >> 4;
#pragma unroll
            for (int i = 0; i < 4; ++i) {
                int r = wm + i * 16 + (lane & 15);
                a[i] = *(const bfrag*)&lA[cur][LDSIDX(r, kc)];
            }
#pragma unroll
            for (int j = 0; j < 4; ++j) {
                int r = wn + j * 16 + (lane & 15);
                b[j] = *(const bfrag*)&lB[cur][LDSIDX(r, kc)];
            }
#pragma unroll
            for (int i = 0; i < 4; ++i)
#pragma unroll
                for (int j = 0; j < 4; ++j)
                    acc[i][j] = __builtin_amdgcn_mfma_f32_16x16x32_bf16(a[i], b[j], acc[i][j], 0, 0, 0);
        }
        __syncthreads();
        cur ^= 1;
    }
#undef STAGE2

    const int colbase = nt * BN + wn;
#pragma unroll
    for (int i = 0; i < 4; ++i) {
        int rbase = wm + i * 16 + ((lane >> 4) << 2);
#pragma unroll
        for (int q = 0; q < 4; ++q) {
            int rl = rbase + q;
            if (rl >= nrows) continue;
            int tok = lTok[rl];
            float w = lPw[rl];
            if (tok < 0) continue;
            size_t rowoff = (size_t)tok * DIM;
#pragma unroll
            for (int j = 0; j < 4; ++j) {
                int col = colbase + j * 16 + (lane & 15);
                atomicAdd(&out[rowoff + col], acc[i][j][q] * w);   // exactly 2 adds/elem, commutative => deterministic
            }
        }
    }
}

extern "C" void kernel_launch(void* const* d_in, const int* in_sizes, int n_in,
                              void* d_out, int out_size, void* d_ws, size_t ws_size,
                              hipStream_t stream) {
    const float* x  = (const float*)d_in[0];
    const float* gw = (const float*)d_in[1];
    const float* w1 = (const float*)d_in[2];
    const float* w2 = (const float*)d_in[3];   // dict order: x, gate_w, w1, w2, w3 !
    const float* w3 = (const float*)d_in[4];
    float* out = (float*)d_out;

    char* ws = (char*)d_ws;
    int*    topi   = (int*)(ws + 0);             // 64 KB
    float*  topw   = (float*)(ws + 65536);       // 64 KB
    int*    perm   = (int*)(ws + 131072);        // 64 KB
    float*  pw     = (float*)(ws + 196608);      // 64 KB
    int*    counts = (int*)(ws + 262144);
    int*    offs   = (int*)(ws + 262144 + 256);
    int*    cursor = (int*)(ws + 262144 + 512);

    const size_t OFF_XB = 524288;                       // xb: 16 MiB
    const size_t OFF_H  = OFF_XB + 16777216;            // H : 128 MiB
    const size_t OFF_WA = OFF_H + 134217728;            // w1b, later w2b: 64 MiB
    const size_t OFF_WB = OFF_WA + 67108864;            // w3b: 64 MiB
    const size_t NEED   = OFF_WB + 67108864;            // 272.5 MiB total

    hipMemsetAsync(counts, 0, 32, stream);
    hipMemsetAsync(out, 0, (size_t)out_size * sizeof(float), stream);

    k_router<<<dim3(TK / 4), 256, 0, stream>>>(x, gw, topi, topw);
    k_count<<<dim3((2 * TK) / 256), 256, 0, stream>>>(topi, counts);
    k_scan<<<dim3(1), 64, 0, stream>>>(counts, offs, cursor);
    k_scatter<<<dim3(TK / 256), 256, 0, stream>>>(topi, topw, cursor, perm, pw);

    if (ws_size >= NEED) {
        ushort* xb  = (ushort*)(ws + OFF_XB);
        ushort* H   = (ushort*)(ws + OFF_H);
        ushort* wA  = (ushort*)(ws + OFF_WA);
        ushort* wB  = (ushort*)(ws + OFF_WB);

        k_cvt<<<dim3((TK * DIM / 8) / 256), 256, 0, stream>>>(x, xb, TK * DIM / 8);
        k_cvt<<<dim3((NE * HID * DIM / 8) / 256), 256, 0, stream>>>(w1, wA, NE * HID * DIM / 8);
        k_cvt<<<dim3((NE * HID * DIM / 8) / 256), 256, 0, stream>>>(w3, wB, NE * HID * DIM / 8);

        k_ffn1<true><<<dim3(TK / BM, HID / BN, NE), 256, 0, stream>>>(
            x, w1, w3, xb, wA, wB, offs, perm, H);

        // w1b dead now; reuse its slot for w2b
        k_cvt<<<dim3((NE * DIM * HID / 8) / 256), 256, 0, stream>>>(w2, wA, NE * DIM * HID / 8);

        k_ffn2<true><<<dim3(TK / BM, DIM / BN, NE), 256, 0, stream>>>(
            H, w2, wA, offs, perm, pw, out);
    } else {
        // fallback: fused-convert path (needs only H); H staged bf16 directly
        ushort* H = (ushort*)(ws + 524288);
        k_ffn1<false><<<dim3(TK / BM, HID / BN, NE), 256, 0, stream>>>(
            x, w1, w3, nullptr, nullptr, nullptr, offs, perm, H);
        k_ffn2<false><<<dim3(TK / BM, DIM / BN, NE), 256, 0, stream>>>(
            H, w2, nullptr, offs, perm, pw, out);
    }
}

// Round 4
// 1497.890 us; speedup vs baseline: 1.2279x; 1.2279x over previous
//
#include <hip/hip_runtime.h>
#include <hip/hip_bf16.h>
#include <cstdint>
#include <cstddef>

#define TK 8192
#define DIM 1024
#define HID 4096
#define NE 8

#define BM 128
#define BN 128
#define BK 32

typedef __attribute__((ext_vector_type(8))) __bf16 bfrag;   // 8 bf16 = 4 VGPR (MFMA A/B operand)
typedef __attribute__((ext_vector_type(4))) float ffrag;    // MFMA C/D operand

static __device__ __forceinline__ ushort f2bf(float f) {
    union { float f; uint32_t u; } v; v.f = f;
    uint32_t r = (v.u + 0x7fffu + ((v.u >> 16) & 1u)) >> 16;   // RNE, finite inputs only
    return (ushort)r;
}

static __device__ __forceinline__ uint4 pack8(float4 a, float4 b) {
    union { ushort u[8]; uint4 q; } pk;
    pk.u[0] = f2bf(a.x); pk.u[1] = f2bf(a.y); pk.u[2] = f2bf(a.z); pk.u[3] = f2bf(a.w);
    pk.u[4] = f2bf(b.x); pk.u[5] = f2bf(b.y); pk.u[6] = f2bf(b.z); pk.u[7] = f2bf(b.w);
    return pk.q;
}

// async global->LDS, 16B per lane; LDS dest = wave-uniform base + lane*16 (m97/m104 semantics)
static __device__ __forceinline__ void gld16(const ushort* g, ushort* l) {
    __builtin_amdgcn_global_load_lds(
        (const __attribute__((address_space(1))) unsigned int*)g,
        (__attribute__((address_space(3))) unsigned int*)l, 16, 0, 0);
}

// raw barrier + counted vmcnt (T4): loads stay in flight across barriers, no drain-0
#define BARRIER() asm volatile("s_barrier" ::: "memory")
#define WAITVM(N) asm volatile("s_waitcnt vmcnt(" #N ")" ::: "memory")

// LDS tile [128 rows][32 bf16], superblocks of 8 rows x 4 chunks(16B):
//   chunk (r,kc) at 16B-slot (r>>3)*32 + kc*8 + (r&7); measured 0 bank conflicts.
// gld16 linear slot s: r = (s>>5)*8 + (s&7), kc = (s>>3)&3.
#define LDSIDX(r, kc) ((((r) >> 3) << 8) + ((kc) << 6) + (((r) & 7) << 3))
#define SLOT_R(s) ((((s) >> 5) << 3) | ((s) & 7))
#define SLOT_KC(s) (((s) >> 3) & 3)

// ---------------- f32 -> bf16 streaming convert (8 elems/thread) ----------------
__global__ __launch_bounds__(256) void k_cvt(const float* __restrict__ src,
                                             ushort* __restrict__ dst, int n8) {
    int i = blockIdx.x * blockDim.x + threadIdx.x;
    if (i >= n8) return;
    const float4* p = (const float4*)src + (size_t)i * 2;
    ((uint4*)dst)[i] = pack8(p[0], p[1]);
}

// ---------------- router: f64-accurate logits, top-2, renormalized weights ----------------
__global__ __launch_bounds__(256) void k_router(const float* __restrict__ x,
                                                const float* __restrict__ gw,
                                                int* __restrict__ topi, float* __restrict__ topw) {
    int t = blockIdx.x * 4 + (threadIdx.x >> 6);
    int lane = threadIdx.x & 63;
    if (t >= TK) return;
    double acc[NE];
#pragma unroll
    for (int e = 0; e < NE; ++e) acc[e] = 0.0;
    const float* xr = x + (size_t)t * DIM;
    for (int k = lane; k < DIM; k += 64) {
        double xv = (double)xr[k];
#pragma unroll
        for (int e = 0; e < NE; ++e) acc[e] += xv * (double)gw[e * DIM + k];
    }
#pragma unroll
    for (int e = 0; e < NE; ++e) {
#pragma unroll
        for (int off = 32; off > 0; off >>= 1) acc[e] += __shfl_xor(acc[e], off);
    }
    if (lane == 0) {
        int i1 = 0;
#pragma unroll
        for (int e = 1; e < NE; ++e) if (acc[e] > acc[i1]) i1 = e;
        int i2 = (i1 == 0) ? 1 : 0;
#pragma unroll
        for (int e = 0; e < NE; ++e) if (e != i1 && acc[e] > acc[i2]) i2 = e;
        double w = 1.0 / (1.0 + exp(acc[i2] - acc[i1]));   // = p1/(p1+p2), Z cancels
        topi[t * 2 + 0] = i1; topi[t * 2 + 1] = i2;
        topw[t * 2 + 0] = (float)w; topw[t * 2 + 1] = (float)(1.0 - w);
    }
}

__global__ void k_count(const int* __restrict__ topi, int* __restrict__ counts) {
    int i = blockIdx.x * blockDim.x + threadIdx.x;
    if (i < 2 * TK) atomicAdd(&counts[topi[i]], 1);
}

__global__ void k_scan(const int* __restrict__ counts, int* __restrict__ offs, int* __restrict__ cursor) {
    if (threadIdx.x == 0 && blockIdx.x == 0) {
        int s = 0;
        for (int e = 0; e < NE; ++e) { offs[e] = s; cursor[e] = s; s += counts[e]; }
        offs[NE] = s;
    }
}

__global__ void k_scatter(const int* __restrict__ topi, const float* __restrict__ topw,
                          int* __restrict__ cursor, int* __restrict__ perm, float* __restrict__ pw) {
    int t = blockIdx.x * blockDim.x + threadIdx.x;
    if (t >= TK) return;
#pragma unroll
    for (int k = 0; k < 2; ++k) {
        int e = topi[t * 2 + k];
        int pos = atomicAdd(&cursor[e], 1);
        perm[pos] = t; pw[pos] = topw[t * 2 + k];
    }
}

// ---------------- GEMM A: H[pos,n] = silu(x@w1^T) * (x@w3^T), bf16 out ----------------
// dbuf + counted-vmcnt raw barriers; XCD-chunked block order (panel-per-L2).
__global__ __launch_bounds__(256) void k_ffn1(const ushort* __restrict__ xb,
                                              const ushort* __restrict__ w1b,
                                              const ushort* __restrict__ w3b,
                                              const int* __restrict__ offs,
                                              const int* __restrict__ perm,
                                              ushort* __restrict__ H) {
    // XCD-chunked swizzle: panel (e,nt) pinned to one XCD, mt-blocks consecutive on it
    const int g = blockIdx.x;            // 0..16383
    const int xcd = g & 7, kk = g >> 3;  // kk < 2048
    const int p  = xcd + ((kk >> 6) << 3);   // panel 0..255
    const int mt = kk & 63;
    const int e  = p >> 5, nt = p & 31;

    const int off = offs[e], end = offs[e + 1];
    const int m0 = off + mt * BM;
    if (m0 >= end) return;
    const int nrows = min(BM, end - m0);

    __shared__ ushort lA[2][BM * BK];
    __shared__ ushort lB1[2][BN * BK];
    __shared__ ushort lB3[2][BN * BK];
    __shared__ int lTok[BM];

    const int tid = threadIdx.x;
    if (tid < BM) lTok[tid] = (tid < nrows) ? perm[m0 + tid] : -1;
    __syncthreads();

    const int lane = tid & 63, wid = tid >> 6;
    const int wm = (wid >> 1) * 64, wn = (wid & 1) * 64;

    ffrag acc1[4][4], acc3[4][4];
#pragma unroll
    for (int i = 0; i < 4; ++i)
#pragma unroll
        for (int j = 0; j < 4; ++j) { acc1[i][j] = (ffrag)0.f; acc3[i][j] = (ffrag)0.f; }

    // per-lane source pointers, slot s = i*256 + tid
    const ushort* pA[2]; const ushort* pB1[2]; const ushort* pB3[2];
    {
        const size_t wbase = (size_t)e * HID * DIM + (size_t)nt * BN * DIM;
#pragma unroll
        for (int i = 0; i < 2; ++i) {
            int s = i * 256 + tid;
            int r = SLOT_R(s), kc = SLOT_KC(s);
            int tok = lTok[r]; if (tok < 0) tok = 0;   // pad rows: finite garbage, discarded
            pA[i]  = xb + (size_t)tok * DIM + kc * 8;
            pB1[i] = w1b + wbase + (size_t)r * DIM + kc * 8;
            pB3[i] = w3b + wbase + (size_t)r * DIM + kc * 8;
        }
    }

#define STAGE1(buf, k0)                                          \
    do {                                                         \
        _Pragma("unroll")                                        \
        for (int i = 0; i < 2; ++i) {                            \
            const int ldso = (i * 256 + wid * 64) * 8;           \
            gld16(pA[i] + (k0), &lA[buf][ldso]);                 \
            gld16(pB1[i] + (k0), &lB1[buf][ldso]);               \
            gld16(pB3[i] + (k0), &lB3[buf][ldso]);               \
        }                                                        \
    } while (0)

#define COMPUTE1(buf)                                                              \
    do {                                                                           \
        bfrag a[4], b1v[4], b3v[4];                                                \
        const int kcc = lane >> 4;                                                 \
        _Pragma("unroll")                                                          \
        for (int i = 0; i < 4; ++i) {                                              \
            int r = wm + i * 16 + (lane & 15);                                     \
            a[i] = *(const bfrag*)&lA[buf][LDSIDX(r, kcc)];                        \
        }                                                                          \
        _Pragma("unroll")                                                          \
        for (int j = 0; j < 4; ++j) {                                              \
            int r = wn + j * 16 + (lane & 15);                                     \
            b1v[j] = *(const bfrag*)&lB1[buf][LDSIDX(r, kcc)];                     \
            b3v[j] = *(const bfrag*)&lB3[buf][LDSIDX(r, kcc)];                     \
        }                                                                          \
        __builtin_amdgcn_s_setprio(1);                                             \
        _Pragma("unroll")                                                          \
        for (int i = 0; i < 4; ++i)                                                \
            _Pragma("unroll")                                                      \
            for (int j = 0; j < 4; ++j) {                                          \
                acc1[i][j] = __builtin_amdgcn_mfma_f32_16x16x32_bf16(a[i], b1v[j], acc1[i][j], 0, 0, 0); \
                acc3[i][j] = __builtin_amdgcn_mfma_f32_16x16x32_bf16(a[i], b3v[j], acc3[i][j], 0, 0, 0); \
            }                                                                      \
        __builtin_amdgcn_s_setprio(0);                                             \
    } while (0)

    STAGE1(0, 0);
    const int NT = DIM / BK;   // 32, even
#pragma unroll 1
    for (int t = 0; t < NT; t += 2) {
        STAGE1(1, (t + 1) * BK);
        WAITVM(6);                 // tile-t loads (own) complete; t+1's 6 stay in flight
        BARRIER();                 // all waves' tile-t data resident
        COMPUTE1(0);
        BARRIER();                 // all reads of buf0 done before next overwrite
        if (t + 2 < NT) {
            STAGE1(0, (t + 2) * BK);
            WAITVM(6);
        } else {
            WAITVM(0);
        }
        BARRIER();
        COMPUTE1(1);
        BARRIER();
    }
#undef STAGE1
#undef COMPUTE1

    // epilogue: silu(h1)*h3 -> bf16 H.  C/D layout: col = lane&15, row = (lane>>4)*4 + q
    const int colbase = nt * BN + wn;
#pragma unroll
    for (int i = 0; i < 4; ++i) {
        int rbase = wm + i * 16 + ((lane >> 4) << 2);
#pragma unroll
        for (int q = 0; q < 4; ++q) {
            int rl = rbase + q;
            if (rl >= nrows) continue;
            size_t rowoff = (size_t)(m0 + rl) * HID;
#pragma unroll
            for (int j = 0; j < 4; ++j) {
                int col = colbase + j * 16 + (lane & 15);
                float h1 = acc1[i][j][q], h3 = acc3[i][j][q];
                float val = (h1 / (1.f + __expf(-h1))) * h3;
                H[rowoff + col] = f2bf(val);
            }
        }
    }
}

// ---------------- GEMM B: out[tok,:] += pw[pos] * (H[pos,:] @ w2^T) ----------------
__global__ __launch_bounds__(256) void k_ffn2(const ushort* __restrict__ H,
                                              const ushort* __restrict__ w2b,
                                              const int* __restrict__ offs,
                                              const int* __restrict__ perm,
                                              const float* __restrict__ pw,
                                              float* __restrict__ out) {
    const int g = blockIdx.x;            // 0..4095
    const int xcd = g & 7, kk = g >> 3;  // kk < 512
    const int p  = xcd + ((kk >> 6) << 3);   // panel 0..63
    const int mt = kk & 63;
    const int e  = p >> 3, nt = p & 7;

    const int off = offs[e], end = offs[e + 1];
    const int m0 = off + mt * BM;
    if (m0 >= end) return;
    const int nrows = min(BM, end - m0);

    __shared__ ushort lA[2][BM * BK];
    __shared__ ushort lB[2][BN * BK];
    __shared__ int lTok[BM];
    __shared__ float lPw[BM];

    const int tid = threadIdx.x;
    if (tid < BM) {
        bool v = tid < nrows;
        lTok[tid] = v ? perm[m0 + tid] : -1;
        lPw[tid]  = v ? pw[m0 + tid] : 0.f;
    }
    __syncthreads();

    const int lane = tid & 63, wid = tid >> 6;
    const int wm = (wid >> 1) * 64, wn = (wid & 1) * 64;

    ffrag acc[4][4];
#pragma unroll
    for (int i = 0; i < 4; ++i)
#pragma unroll
        for (int j = 0; j < 4; ++j) acc[i][j] = (ffrag)0.f;

    const ushort* pA[2]; const ushort* pB[2];
    {
        const size_t wbase = (size_t)e * DIM * HID + (size_t)nt * BN * HID;
#pragma unroll
        for (int i = 0; i < 2; ++i) {
            int s = i * 256 + tid;
            int r = SLOT_R(s), kc = SLOT_KC(s);
            int pos = m0 + r; if (pos > 2 * TK - 1) pos = 2 * TK - 1;   // clamp into H
            pA[i] = H + (size_t)pos * HID + kc * 8;
            pB[i] = w2b + wbase + (size_t)r * HID + kc * 8;
        }
    }

#define STAGE2(buf, k0)                                          \
    do {                                                         \
        _Pragma("unroll")                                        \
        for (int i = 0; i < 2; ++i) {                            \
            const int ldso = (i * 256 + wid * 64) * 8;           \
            gld16(pA[i] + (k0), &lA[buf][ldso]);                 \
            gld16(pB[i] + (k0), &lB[buf][ldso]);                 \
        }                                                        \
    } while (0)

#define COMPUTE2(buf)                                                              \
    do {                                                                           \
        bfrag a[4], b[4];                                                          \
        const int kcc = lane >> 4;                                                 \
        _Pragma("unroll")                                                          \
        for (int i = 0; i < 4; ++i) {                                              \
            int r = wm + i * 16 + (lane & 15);                                     \
            a[i] = *(const bfrag*)&lA[buf][LDSIDX(r, kcc)];                        \
        }                                                                          \
        _Pragma("unroll")                                                          \
        for (int j = 0; j < 4; ++j) {                                              \
            int r = wn + j * 16 + (lane & 15);                                     \
            b[j] = *(const bfrag*)&lB[buf][LDSIDX(r, kcc)];                        \
        }                                                                          \
        __builtin_amdgcn_s_setprio(1);                                             \
        _Pragma("unroll")                                                          \
        for (int i = 0; i < 4; ++i)                                                \
            _Pragma("unroll")                                                      \
            for (int j = 0; j < 4; ++j)                                            \
                acc[i][j] = __builtin_amdgcn_mfma_f32_16x16x32_bf16(a[i], b[j], acc[i][j], 0, 0, 0); \
        __builtin_amdgcn_s_setprio(0);                                             \
    } while (0)

    STAGE2(0, 0);
    const int NT = HID / BK;   // 128, even
#pragma unroll 1
    for (int t = 0; t < NT; t += 2) {
        STAGE2(1, (t + 1) * BK);
        WAITVM(4);
        BARRIER();
        COMPUTE2(0);
        BARRIER();
        if (t + 2 < NT) {
            STAGE2(0, (t + 2) * BK);
            WAITVM(4);
        } else {
            WAITVM(0);
        }
        BARRIER();
        COMPUTE2(1);
        BARRIER();
    }
#undef STAGE2
#undef COMPUTE2

    const int colbase = nt * BN + wn;
#pragma unroll
    for (int i = 0; i < 4; ++i) {
        int rbase = wm + i * 16 + ((lane >> 4) << 2);
#pragma unroll
        for (int q = 0; q < 4; ++q) {
            int rl = rbase + q;
            if (rl >= nrows) continue;
            int tok = lTok[rl];
            float w = lPw[rl];
            if (tok < 0) continue;
            size_t rowoff = (size_t)tok * DIM;
#pragma unroll
            for (int j = 0; j < 4; ++j) {
                int col = colbase + j * 16 + (lane & 15);
                atomicAdd(&out[rowoff + col], acc[i][j][q] * w);   // exactly 2 adds/elem, deterministic
            }
        }
    }
}

extern "C" void kernel_launch(void* const* d_in, const int* in_sizes, int n_in,
                              void* d_out, int out_size, void* d_ws, size_t ws_size,
                              hipStream_t stream) {
    const float* x  = (const float*)d_in[0];
    const float* gw = (const float*)d_in[1];
    const float* w1 = (const float*)d_in[2];
    const float* w2 = (const float*)d_in[3];   // dict order: x, gate_w, w1, w2, w3 !
    const float* w3 = (const float*)d_in[4];
    float* out = (float*)d_out;

    char* ws = (char*)d_ws;
    int*    topi   = (int*)(ws + 0);             // 64 KB
    float*  topw   = (float*)(ws + 65536);       // 64 KB
    int*    perm   = (int*)(ws + 131072);        // 64 KB
    float*  pw     = (float*)(ws + 196608);      // 64 KB
    int*    counts = (int*)(ws + 262144);
    int*    offs   = (int*)(ws + 262144 + 256);
    int*    cursor = (int*)(ws + 262144 + 512);

    const size_t OFF_XB = 524288;                       // xb: 16 MiB
    const size_t OFF_H  = OFF_XB + 16777216;            // H : 128 MiB
    const size_t OFF_WA = OFF_H + 134217728;            // w1b, later w2b: 64 MiB
    const size_t OFF_WB = OFF_WA + 67108864;            // w3b: 64 MiB

    ushort* xb  = (ushort*)(ws + OFF_XB);
    ushort* H   = (ushort*)(ws + OFF_H);
    ushort* wA  = (ushort*)(ws + OFF_WA);
    ushort* wB  = (ushort*)(ws + OFF_WB);

    hipMemsetAsync(counts, 0, 32, stream);
    hipMemsetAsync(out, 0, (size_t)out_size * sizeof(float), stream);

    k_router<<<dim3(TK / 4), 256, 0, stream>>>(x, gw, topi, topw);
    k_count<<<dim3((2 * TK) / 256), 256, 0, stream>>>(topi, counts);
    k_scan<<<dim3(1), 64, 0, stream>>>(counts, offs, cursor);
    k_scatter<<<dim3(TK / 256), 256, 0, stream>>>(topi, topw, cursor, perm, pw);

    k_cvt<<<dim3((TK * DIM / 8) / 256), 256, 0, stream>>>(x, xb, TK * DIM / 8);
    k_cvt<<<dim3((NE * HID * DIM / 8) / 256), 256, 0, stream>>>(w1, wA, NE * HID * DIM / 8);
    k_cvt<<<dim3((NE * HID * DIM / 8) / 256), 256, 0, stream>>>(w3, wB, NE * HID * DIM / 8);

    k_ffn1<<<dim3(16384), 256, 0, stream>>>(xb, wA, wB, offs, perm, H);

    // w1b dead now; reuse its slot for w2b
    k_cvt<<<dim3((NE * DIM * HID / 8) / 256), 256, 0, stream>>>(w2, wA, NE * DIM * HID / 8);

    k_ffn2<<<dim3(4096), 256, 0, stream>>>(H, wA, offs, perm, pw, out);
}

// Round 5
// 1202.202 us; speedup vs baseline: 1.5299x; 1.2460x over previous
//
#include <hip/hip_runtime.h>
#include <hip/hip_bf16.h>
#include <cstdint>
#include <cstddef>

#define TK 8192
#define DIM 1024
#define HID 4096
#define NE 8

#define BMT 256     // M tile
#define BNT 256     // N tile
#define BKT 32      // K step
#define NBUF 4      // LDS ring: 3 tiles in flight + 1 being read

typedef __attribute__((ext_vector_type(8))) __bf16 bfrag;   // 8 bf16 (MFMA A/B operand)
typedef __attribute__((ext_vector_type(4))) float ffrag;    // MFMA C/D operand

static __device__ __forceinline__ ushort f2bf(float f) {
    union { float f; uint32_t u; } v; v.f = f;
    uint32_t r = (v.u + 0x7fffu + ((v.u >> 16) & 1u)) >> 16;   // RNE, finite inputs only
    return (ushort)r;
}

static __device__ __forceinline__ uint4 pack8(float4 a, float4 b) {
    union { ushort u[8]; uint4 q; } pk;
    pk.u[0] = f2bf(a.x); pk.u[1] = f2bf(a.y); pk.u[2] = f2bf(a.z); pk.u[3] = f2bf(a.w);
    pk.u[4] = f2bf(b.x); pk.u[5] = f2bf(b.y); pk.u[6] = f2bf(b.z); pk.u[7] = f2bf(b.w);
    return pk.q;
}

// async global->LDS, 16B/lane; LDS dest = wave-uniform base + lane*16
static __device__ __forceinline__ void gld16(const ushort* g, ushort* l) {
    __builtin_amdgcn_global_load_lds(
        (const __attribute__((address_space(1))) unsigned int*)g,
        (__attribute__((address_space(3))) unsigned int*)l, 16, 0, 0);
}

#define BARRIER() asm volatile("s_barrier" ::: "memory")
#define WAITVM(N) asm volatile("s_waitcnt vmcnt(" #N ")" ::: "memory")

// LDS tile [256 rows][32 bf16], superblocks of 8 rows x 4 chunks(16B):
//   chunk (r,kc) at 16B-slot (r>>3)*32 + kc*8 + (r&7); 0 conflicts measured (r3/r4).
// gld16 linear slot s: r = (s>>5)*8 + (s&7), kc = (s>>3)&3.
#define LDSIDX(r, kc) ((((r) >> 3) << 8) + ((kc) << 6) + (((r) & 7) << 3))
#define SLOT_R(s)  ((((s) >> 5) << 3) | ((s) & 7))
#define SLOT_KC(s) (((s) >> 3) & 3)

// ---------------- f32 -> bf16 streaming convert ----------------
__global__ __launch_bounds__(256) void k_cvt(const float* __restrict__ src,
                                             ushort* __restrict__ dst, int n8) {
    int i = blockIdx.x * blockDim.x + threadIdx.x;
    if (i >= n8) return;
    const float4* p = (const float4*)src + (size_t)i * 2;
    ((uint4*)dst)[i] = pack8(p[0], p[1]);
}

// ---------------- router: f64-accurate logits, top-2, renormalized ----------------
__global__ __launch_bounds__(256) void k_router(const float* __restrict__ x,
                                                const float* __restrict__ gw,
                                                int* __restrict__ topi, float* __restrict__ topw) {
    int t = blockIdx.x * 4 + (threadIdx.x >> 6);
    int lane = threadIdx.x & 63;
    if (t >= TK) return;
    double acc[NE];
#pragma unroll
    for (int e = 0; e < NE; ++e) acc[e] = 0.0;
    const float* xr = x + (size_t)t * DIM;
    for (int k = lane; k < DIM; k += 64) {
        double xv = (double)xr[k];
#pragma unroll
        for (int e = 0; e < NE; ++e) acc[e] += xv * (double)gw[e * DIM + k];
    }
#pragma unroll
    for (int e = 0; e < NE; ++e) {
#pragma unroll
        for (int off = 32; off > 0; off >>= 1) acc[e] += __shfl_xor(acc[e], off);
    }
    if (lane == 0) {
        int i1 = 0;
#pragma unroll
        for (int e = 1; e < NE; ++e) if (acc[e] > acc[i1]) i1 = e;
        int i2 = (i1 == 0) ? 1 : 0;
#pragma unroll
        for (int e = 0; e < NE; ++e) if (e != i1 && acc[e] > acc[i2]) i2 = e;
        double w = 1.0 / (1.0 + exp(acc[i2] - acc[i1]));
        topi[t * 2 + 0] = i1; topi[t * 2 + 1] = i2;
        topw[t * 2 + 0] = (float)w; topw[t * 2 + 1] = (float)(1.0 - w);
    }
}

__global__ void k_count(const int* __restrict__ topi, int* __restrict__ counts) {
    int i = blockIdx.x * blockDim.x + threadIdx.x;
    if (i < 2 * TK) atomicAdd(&counts[topi[i]], 1);
}

__global__ void k_scan(const int* __restrict__ counts, int* __restrict__ offs, int* __restrict__ cursor) {
    if (threadIdx.x == 0 && blockIdx.x == 0) {
        int s = 0;
        for (int e = 0; e < NE; ++e) { offs[e] = s; cursor[e] = s; s += counts[e]; }
        offs[NE] = s;
    }
}

__global__ void k_scatter(const int* __restrict__ topi, const float* __restrict__ topw,
                          int* __restrict__ cursor, int* __restrict__ perm, float* __restrict__ pw) {
    int t = blockIdx.x * blockDim.x + threadIdx.x;
    if (t >= TK) return;
#pragma unroll
    for (int k = 0; k < 2; ++k) {
        int e = topi[t * 2 + k];
        int pos = atomicAdd(&cursor[e], 1);
        perm[pos] = t; pw[pos] = topw[t * 2 + k];
    }
}

// ---------------- GEMM A (fused): H = silu(x@w1^T) * (x@w3^T) ----------------
// 256x256 tile: B rows interleave w1/w3 in 16-row groups so (h1,h3) pairs are wave-local.
// 8 waves (2M x 4N), per-wave 128x64. 4-deep LDS ring, tile t staged at iter t-3.
__global__ __launch_bounds__(512, 2) void k_ffn1(const ushort* __restrict__ xb,
                                                 const ushort* __restrict__ w1b,
                                                 const ushort* __restrict__ w3b,
                                                 const int* __restrict__ offs,
                                                 const int* __restrict__ perm,
                                                 ushort* __restrict__ H) {
    // XCD-chunked: panel (e,nt) pinned to one XCD, mt consecutive on it
    const int g = blockIdx.x;                 // 0..8191
    const int xcd = g & 7, kk = g >> 3;       // kk 0..1023
    const int p  = xcd + ((kk >> 5) << 3);    // panel 0..255
    const int mt = kk & 31;
    const int e  = p >> 5, nt = p & 31;

    const int off = offs[e], end = offs[e + 1];
    const int m0 = off + mt * BMT;
    if (m0 >= end) return;
    const int nrows = min(BMT, end - m0);

    __shared__ ushort lA[NBUF][BMT * BKT];    // 4 x 16 KiB
    __shared__ ushort lB[NBUF][BNT * BKT];    // 4 x 16 KiB
    __shared__ int lTok[BMT];

    const int tid = threadIdx.x;
    if (tid < BMT) lTok[tid] = (tid < nrows) ? perm[m0 + tid] : -1;
    __syncthreads();

    const int lane = tid & 63, wid = tid >> 6;
    const int wm = (wid >> 2) * 128;          // M-wave: 0 / 128
    const int wn = (wid & 3) * 64;            // N-wave: 0/64/128/192

    ffrag acc[8][4];
#pragma unroll
    for (int i = 0; i < 8; ++i)
#pragma unroll
        for (int j = 0; j < 4; ++j) acc[i][j] = (ffrag)0.f;

    // per-lane source pointers, slot s = i*512 + tid (1024 chunks per 256x32 tile)
    const ushort* pA[2]; const ushort* pB[2];
    {
        const size_t ebase = (size_t)e * HID * DIM;
#pragma unroll
        for (int i = 0; i < 2; ++i) {
            int s = i * 512 + tid;
            int r = SLOT_R(s), kc = SLOT_KC(s);
            int tok = lTok[r]; if (tok < 0) tok = 0;           // pad rows: discarded later
            pA[i] = xb + (size_t)tok * DIM + kc * 8;
            int gg = r >> 4;                                   // 16-row group
            int h  = ((gg >> 1) << 4) | (r & 15);              // hidden col within panel
            const ushort* wsrc = (gg & 1) ? w3b : w1b;         // even group=w1, odd=w3
            pB[i] = wsrc + ebase + (size_t)(nt * 128 + h) * DIM + kc * 8;
        }
    }

#define STG1A(buf, k0) do { \
        gld16(pA[0] + (k0), &lA[buf][(wid * 64) * 8]); \
        gld16(pA[1] + (k0), &lA[buf][(512 + wid * 64) * 8]); } while (0)
#define STG1B(buf, k0) do { \
        gld16(pB[0] + (k0), &lB[buf][(wid * 64) * 8]); \
        gld16(pB[1] + (k0), &lB[buf][(512 + wid * 64) * 8]); } while (0)

    // prologue: tiles 0,1,2 in flight (12 loads)
    STG1A(0, 0);  STG1B(0, 0);
    STG1A(1, 32); STG1B(1, 32);
    STG1A(2, 64); STG1B(2, 64);

    const int NT = DIM / BKT;   // 32
#pragma unroll 1
    for (int t = 0; t < NT; ++t) {
        const int cbuf = t & 3, sbuf = (t + 3) & 3;
        const bool stg = (t + 3) < NT;
        const int sk0 = (t + 3) * BKT;
        if (t + 2 < NT) { WAITVM(8); } else if (t + 1 < NT) { WAITVM(4); } else { WAITVM(0); }
        BARRIER();                            // tile t resident for all waves
        if (stg) STG1A(sbuf, sk0);
        const int kcc = lane >> 4;
        bfrag a[8], b[4];
#pragma unroll
        for (int j = 0; j < 4; ++j)
            b[j] = *(const bfrag*)&lB[cbuf][LDSIDX(wn + j * 16 + (lane & 15), kcc)];
#pragma unroll
        for (int i = 0; i < 4; ++i)
            a[i] = *(const bfrag*)&lA[cbuf][LDSIDX(wm + i * 16 + (lane & 15), kcc)];
        __builtin_amdgcn_s_setprio(1);
#pragma unroll
        for (int i = 0; i < 4; ++i)
#pragma unroll
            for (int j = 0; j < 4; ++j)
                acc[i][j] = __builtin_amdgcn_mfma_f32_16x16x32_bf16(a[i], b[j], acc[i][j], 0, 0, 0);
        __builtin_amdgcn_s_setprio(0);
        if (stg) STG1B(sbuf, sk0);
#pragma unroll
        for (int i = 4; i < 8; ++i)
            a[i] = *(const bfrag*)&lA[cbuf][LDSIDX(wm + i * 16 + (lane & 15), kcc)];
        __builtin_amdgcn_s_setprio(1);
#pragma unroll
        for (int i = 4; i < 8; ++i)
#pragma unroll
            for (int j = 0; j < 4; ++j)
                acc[i][j] = __builtin_amdgcn_mfma_f32_16x16x32_bf16(a[i], b[j], acc[i][j], 0, 0, 0);
        __builtin_amdgcn_s_setprio(0);
    }
#undef STG1A
#undef STG1B

    // epilogue: frag pairs (j, j+1) = (h1, h3) for the same 16 hidden cols
#pragma unroll
    for (int i = 0; i < 8; ++i) {
        int rbase = wm + i * 16 + ((lane >> 4) << 2);
#pragma unroll
        for (int q = 0; q < 4; ++q) {
            int rl = rbase + q;
            if (rl >= nrows) continue;
            size_t rowoff = (size_t)(m0 + rl) * HID;
#pragma unroll
            for (int jf = 0; jf < 4; jf += 2) {
                int gg = (wn >> 4) + jf;
                int col = nt * 128 + ((gg >> 1) << 4) + (lane & 15);
                float h1 = acc[i][jf][q], h3 = acc[i][jf + 1][q];
                float val = (h1 / (1.f + __expf(-h1))) * h3;
                H[rowoff + col] = f2bf(val);
            }
        }
    }
}

// ---------------- GEMM B: out[tok,:] += pw[pos] * (H[pos,:] @ w2^T) ----------------
__global__ __launch_bounds__(512, 2) void k_ffn2(const ushort* __restrict__ H,
                                                 const ushort* __restrict__ w2b,
                                                 const int* __restrict__ offs,
                                                 const int* __restrict__ perm,
                                                 const float* __restrict__ pw,
                                                 float* __restrict__ out) {
    const int g = blockIdx.x;                 // 0..1023
    const int xcd = g & 7, kk = g >> 3;       // kk 0..127
    const int p  = xcd + ((kk >> 5) << 3);    // panel 0..31
    const int mt = kk & 31;
    const int e  = p >> 2, nt = p & 3;

    const int off = offs[e], end = offs[e + 1];
    const int m0 = off + mt * BMT;
    if (m0 >= end) return;
    const int nrows = min(BMT, end - m0);

    __shared__ ushort lA[NBUF][BMT * BKT];
    __shared__ ushort lB[NBUF][BNT * BKT];
    __shared__ int lTok[BMT];
    __shared__ float lPw[BMT];

    const int tid = threadIdx.x;
    if (tid < BMT) {
        bool v = tid < nrows;
        lTok[tid] = v ? perm[m0 + tid] : -1;
        lPw[tid]  = v ? pw[m0 + tid] : 0.f;
    }
    __syncthreads();

    const int lane = tid & 63, wid = tid >> 6;
    const int wm = (wid >> 2) * 128;
    const int wn = (wid & 3) * 64;

    ffrag acc[8][4];
#pragma unroll
    for (int i = 0; i < 8; ++i)
#pragma unroll
        for (int j = 0; j < 4; ++j) acc[i][j] = (ffrag)0.f;

    const ushort* pA[2]; const ushort* pB[2];
    {
        const size_t ebase = (size_t)e * DIM * HID;
#pragma unroll
        for (int i = 0; i < 2; ++i) {
            int s = i * 512 + tid;
            int r = SLOT_R(s), kc = SLOT_KC(s);
            int pos = m0 + r; if (pos > 2 * TK - 1) pos = 2 * TK - 1;   // clamp into H
            pA[i] = H + (size_t)pos * HID + kc * 8;
            pB[i] = w2b + ebase + (size_t)(nt * BNT + r) * HID + kc * 8;
        }
    }

#define STG2A(buf, k0) do { \
        gld16(pA[0] + (k0), &lA[buf][(wid * 64) * 8]); \
        gld16(pA[1] + (k0), &lA[buf][(512 + wid * 64) * 8]); } while (0)
#define STG2B(buf, k0) do { \
        gld16(pB[0] + (k0), &lB[buf][(wid * 64) * 8]); \
        gld16(pB[1] + (k0), &lB[buf][(512 + wid * 64) * 8]); } while (0)

    STG2A(0, 0);  STG2B(0, 0);
    STG2A(1, 32); STG2B(1, 32);
    STG2A(2, 64); STG2B(2, 64);

    const int NT = HID / BKT;   // 128
#pragma unroll 1
    for (int t = 0; t < NT; ++t) {
        const int cbuf = t & 3, sbuf = (t + 3) & 3;
        const bool stg = (t + 3) < NT;
        const int sk0 = (t + 3) * BKT;
        if (t + 2 < NT) { WAITVM(8); } else if (t + 1 < NT) { WAITVM(4); } else { WAITVM(0); }
        BARRIER();
        if (stg) STG2A(sbuf, sk0);
        const int kcc = lane >> 4;
        bfrag a[8], b[4];
#pragma unroll
        for (int j = 0; j < 4; ++j)
            b[j] = *(const bfrag*)&lB[cbuf][LDSIDX(wn + j * 16 + (lane & 15), kcc)];
#pragma unroll
        for (int i = 0; i < 4; ++i)
            a[i] = *(const bfrag*)&lA[cbuf][LDSIDX(wm + i * 16 + (lane & 15), kcc)];
        __builtin_amdgcn_s_setprio(1);
#pragma unroll
        for (int i = 0; i < 4; ++i)
#pragma unroll
            for (int j = 0; j < 4; ++j)
                acc[i][j] = __builtin_amdgcn_mfma_f32_16x16x32_bf16(a[i], b[j], acc[i][j], 0, 0, 0);
        __builtin_amdgcn_s_setprio(0);
        if (stg) STG2B(sbuf, sk0);
#pragma unroll
        for (int i = 4; i < 8; ++i)
            a[i] = *(const bfrag*)&lA[cbuf][LDSIDX(wm + i * 16 + (lane & 15), kcc)];
        __builtin_amdgcn_s_setprio(1);
#pragma unroll
        for (int i = 4; i < 8; ++i)
#pragma unroll
            for (int j = 0; j < 4; ++j)
                acc[i][j] = __builtin_amdgcn_mfma_f32_16x16x32_bf16(a[i], b[j], acc[i][j], 0, 0, 0);
        __builtin_amdgcn_s_setprio(0);
    }
#undef STG2A
#undef STG2B

    const int colbase = nt * BNT + wn;
#pragma unroll
    for (int i = 0; i < 8; ++i) {
        int rbase = wm + i * 16 + ((lane >> 4) << 2);
#pragma unroll
        for (int q = 0; q < 4; ++q) {
            int rl = rbase + q;
            if (rl >= nrows) continue;
            int tok = lTok[rl];
            float w = lPw[rl];
            if (tok < 0) continue;
            size_t rowoff = (size_t)tok * DIM;
#pragma unroll
            for (int j = 0; j < 4; ++j) {
                int col = colbase + j * 16 + (lane & 15);
                atomicAdd(&out[rowoff + col], acc[i][j][q] * w);   // 2 adds/elem, deterministic
            }
        }
    }
}

extern "C" void kernel_launch(void* const* d_in, const int* in_sizes, int n_in,
                              void* d_out, int out_size, void* d_ws, size_t ws_size,
                              hipStream_t stream) {
    const float* x  = (const float*)d_in[0];
    const float* gw = (const float*)d_in[1];
    const float* w1 = (const float*)d_in[2];
    const float* w2 = (const float*)d_in[3];   // dict order: x, gate_w, w1, w2, w3 !
    const float* w3 = (const float*)d_in[4];
    float* out = (float*)d_out;

    char* ws = (char*)d_ws;
    int*    topi   = (int*)(ws + 0);
    float*  topw   = (float*)(ws + 65536);
    int*    perm   = (int*)(ws + 131072);
    float*  pw     = (float*)(ws + 196608);
    int*    counts = (int*)(ws + 262144);
    int*    offs   = (int*)(ws + 262144 + 256);
    int*    cursor = (int*)(ws + 262144 + 512);

    const size_t OFF_XB = 524288;                       // xb: 16 MiB
    const size_t OFF_H  = OFF_XB + 16777216;            // H : 128 MiB
    const size_t OFF_WA = OFF_H + 134217728;            // w1b, later w2b: 64 MiB
    const size_t OFF_WB = OFF_WA + 67108864;            // w3b: 64 MiB

    ushort* xb  = (ushort*)(ws + OFF_XB);
    ushort* H   = (ushort*)(ws + OFF_H);
    ushort* wA  = (ushort*)(ws + OFF_WA);
    ushort* wB  = (ushort*)(ws + OFF_WB);

    hipMemsetAsync(counts, 0, 32, stream);
    hipMemsetAsync(out, 0, (size_t)out_size * sizeof(float), stream);

    k_router<<<dim3(TK / 4), 256, 0, stream>>>(x, gw, topi, topw);
    k_count<<<dim3((2 * TK) / 256), 256, 0, stream>>>(topi, counts);
    k_scan<<<dim3(1), 64, 0, stream>>>(counts, offs, cursor);
    k_scatter<<<dim3(TK / 256), 256, 0, stream>>>(topi, topw, cursor, perm, pw);

    k_cvt<<<dim3((TK * DIM / 8) / 256), 256, 0, stream>>>(x, xb, TK * DIM / 8);
    k_cvt<<<dim3((NE * HID * DIM / 8) / 256), 256, 0, stream>>>(w1, wA, NE * HID * DIM / 8);
    k_cvt<<<dim3((NE * HID * DIM / 8) / 256), 256, 0, stream>>>(w3, wB, NE * HID * DIM / 8);

    k_ffn1<<<dim3(8192), 512, 0, stream>>>(xb, wA, wB, offs, perm, H);

    // w1b dead now; reuse its slot for w2b
    k_cvt<<<dim3((NE * DIM * HID / 8) / 256), 256, 0, stream>>>(w2, wA, NE * DIM * HID / 8);

    k_ffn2<<<dim3(1024), 512, 0, stream>>>(H, wA, offs, perm, pw, out);
}

// Round 6
// 1020.858 us; speedup vs baseline: 1.8016x; 1.1776x over previous
//
#include <hip/hip_runtime.h>
#include <hip/hip_bf16.h>
#include <cstdint>
#include <cstddef>

#define TK 8192
#define DIM 1024
#define HID 4096
#define NE 8

#define BMT 256     // M tile
#define BNT 256     // N tile
#define SK 32       // K subtile (half of a 64-K-tile)
#define NBUF 4      // subtile ring

typedef __attribute__((ext_vector_type(8))) __bf16 bfrag;
typedef __attribute__((ext_vector_type(4))) float ffrag;

static __device__ __forceinline__ ushort f2bf(float f) {
    union { float f; uint32_t u; } v; v.f = f;
    uint32_t r = (v.u + 0x7fffu + ((v.u >> 16) & 1u)) >> 16;   // RNE, finite only
    return (ushort)r;
}

static __device__ __forceinline__ uint4 pack8(float4 a, float4 b) {
    union { ushort u[8]; uint4 q; } pk;
    pk.u[0] = f2bf(a.x); pk.u[1] = f2bf(a.y); pk.u[2] = f2bf(a.z); pk.u[3] = f2bf(a.w);
    pk.u[4] = f2bf(b.x); pk.u[5] = f2bf(b.y); pk.u[6] = f2bf(b.z); pk.u[7] = f2bf(b.w);
    return pk.q;
}

static __device__ __forceinline__ void gld16(const ushort* g, ushort* l) {
    __builtin_amdgcn_global_load_lds(
        (const __attribute__((address_space(1))) unsigned int*)g,
        (__attribute__((address_space(3))) unsigned int*)l, 16, 0, 0);
}

#define BARRIER() asm volatile("s_barrier" ::: "memory")
#define WAITVM(N) asm volatile("s_waitcnt vmcnt(" #N ")" ::: "memory")

// LDS subtile [256 rows][32 bf16], superblocks of 8 rows x 4 chunks(16B):
// chunk (r,kc) at 16B-slot (r>>3)*32 + kc*8 + (r&7); 0 bank conflicts measured (r3-r5).
// gld16 linear slot s: r = (s>>5)*8 + (s&7), kc = (s>>3)&3.
#define LDSIDX(r, kc) ((((r) >> 3) << 8) + ((kc) << 6) + (((r) & 7) << 3))
#define SLOT_R(s)  ((((s) >> 5) << 3) | ((s) & 7))
#define SLOT_KC(s) (((s) >> 3) & 3)

// ---------------- f32 -> bf16 streaming convert ----------------
__global__ __launch_bounds__(256) void k_cvt(const float* __restrict__ src,
                                             ushort* __restrict__ dst, int n8) {
    int i = blockIdx.x * blockDim.x + threadIdx.x;
    if (i >= n8) return;
    const float4* p = (const float4*)src + (size_t)i * 2;
    ((uint4*)dst)[i] = pack8(p[0], p[1]);
}

// ---------------- router: f64-accurate logits, top-2, renormalized ----------------
__global__ __launch_bounds__(256) void k_router(const float* __restrict__ x,
                                                const float* __restrict__ gw,
                                                int* __restrict__ topi, float* __restrict__ topw) {
    int t = blockIdx.x * 4 + (threadIdx.x >> 6);
    int lane = threadIdx.x & 63;
    if (t >= TK) return;
    double acc[NE];
#pragma unroll
    for (int e = 0; e < NE; ++e) acc[e] = 0.0;
    const float* xr = x + (size_t)t * DIM;
    for (int k = lane; k < DIM; k += 64) {
        double xv = (double)xr[k];
#pragma unroll
        for (int e = 0; e < NE; ++e) acc[e] += xv * (double)gw[e * DIM + k];
    }
#pragma unroll
    for (int e = 0; e < NE; ++e) {
#pragma unroll
        for (int off = 32; off > 0; off >>= 1) acc[e] += __shfl_xor(acc[e], off);
    }
    if (lane == 0) {
        int i1 = 0;
#pragma unroll
        for (int e = 1; e < NE; ++e) if (acc[e] > acc[i1]) i1 = e;
        int i2 = (i1 == 0) ? 1 : 0;
#pragma unroll
        for (int e = 0; e < NE; ++e) if (e != i1 && acc[e] > acc[i2]) i2 = e;
        double w = 1.0 / (1.0 + exp(acc[i2] - acc[i1]));
        topi[t * 2 + 0] = i1; topi[t * 2 + 1] = i2;
        topw[t * 2 + 0] = (float)w; topw[t * 2 + 1] = (float)(1.0 - w);
    }
}

__global__ void k_count(const int* __restrict__ topi, int* __restrict__ counts) {
    int i = blockIdx.x * blockDim.x + threadIdx.x;
    if (i < 2 * TK) atomicAdd(&counts[topi[i]], 1);
}

__global__ void k_scan(const int* __restrict__ counts, int* __restrict__ offs, int* __restrict__ cursor) {
    if (threadIdx.x == 0 && blockIdx.x == 0) {
        int s = 0;
        for (int e = 0; e < NE; ++e) { offs[e] = s; cursor[e] = s; s += counts[e]; }
        offs[NE] = s;
    }
}

__global__ void k_scatter(const int* __restrict__ topi, const float* __restrict__ topw,
                          int* __restrict__ cursor, int* __restrict__ perm, float* __restrict__ pw) {
    int t = blockIdx.x * blockDim.x + threadIdx.x;
    if (t >= TK) return;
#pragma unroll
    for (int k = 0; k < 2; ++k) {
        int e = topi[t * 2 + k];
        int pos = atomicAdd(&cursor[e], 1);
        perm[pos] = t; pw[pos] = topw[t * 2 + k];
    }
}

// ================= 8-phase GEMM cores =================
// Phase: {ds_read quadrant | stage 1 half-tile (2 gld16) | WAITVM(8) | bar |
//         setprio1; 16 MFMA; setprio0 | bar}.  2 loads/phase + vmcnt(8) every
// phase => loads issued >=5 phases ago retired; subtiles staged 5-6 phases
// before first read (strict ledger, incl. prologue & tail).

// ---------------- GEMM A (fused): H = silu(x@w1^T) * (x@w3^T) ----------------
__global__ __launch_bounds__(512, 2) void k_ffn1(const ushort* __restrict__ xb,
                                                 const ushort* __restrict__ w1b,
                                                 const ushort* __restrict__ w3b,
                                                 const int* __restrict__ offs,
                                                 const int* __restrict__ perm,
                                                 ushort* __restrict__ H) {
    // XCD-chunked: panel (e,nt) pinned to one XCD, mt consecutive on it
    const int g = blockIdx.x;                 // 0..8191
    const int xcd = g & 7, kk = g >> 3;
    const int p  = xcd + ((kk >> 5) << 3);    // panel 0..255
    const int mt = kk & 31;
    const int e  = p >> 5, nt = p & 31;

    const int off = offs[e], end = offs[e + 1];
    const int m0 = off + mt * BMT;
    if (m0 >= end) return;
    const int nrows = min(BMT, end - m0);

    __shared__ ushort lA[NBUF][BMT * SK];     // 4 x 16 KiB
    __shared__ ushort lB[NBUF][BNT * SK];     // 4 x 16 KiB
    __shared__ int lTok[BMT];

    const int tid = threadIdx.x;
    if (tid < BMT) lTok[tid] = (tid < nrows) ? perm[m0 + tid] : -1;
    __syncthreads();

    const int lane = tid & 63, wid = tid >> 6;
    const int l15 = lane & 15;
    const int wm = (wid >> 2) * 128;          // 0 / 128
    const int wn = (wid & 3) * 64;            // 0/64/128/192

    ffrag acc[8][4];
#pragma unroll
    for (int i = 0; i < 8; ++i)
#pragma unroll
        for (int j = 0; j < 4; ++j) acc[i][j] = (ffrag)0.f;

    const ushort* pA[2]; const ushort* pB[2];
    {
        const size_t ebase = (size_t)e * HID * DIM;
#pragma unroll
        for (int i = 0; i < 2; ++i) {
            int s = i * 512 + tid;
            int r = SLOT_R(s), kc = SLOT_KC(s);
            int tok = lTok[r]; if (tok < 0) tok = 0;           // pad rows discarded later
            pA[i] = xb + (size_t)tok * DIM + kc * 8;
            int gg = r >> 4;                                   // 16-row group
            int h  = ((gg >> 1) << 4) | (r & 15);              // hidden col within panel
            const ushort* wsrc = (gg & 1) ? w3b : w1b;         // even=w1, odd=w3
            pB[i] = wsrc + ebase + (size_t)(nt * 128 + h) * DIM + kc * 8;
        }
    }

    const int NSUB = DIM / SK;   // 32

#define STGA(buf, sx) do { if ((sx) < NSUB) { \
        gld16(pA[0] + (sx) * SK, &lA[buf][(wid * 64) * 8]); \
        gld16(pA[1] + (sx) * SK, &lA[buf][(512 + wid * 64) * 8]); } } while (0)
#define STGB(buf, sx) do { if ((sx) < NSUB) { \
        gld16(pB[0] + (sx) * SK, &lB[buf][(wid * 64) * 8]); \
        gld16(pB[1] + (sx) * SK, &lB[buf][(512 + wid * 64) * 8]); } } while (0)

    bfrag a[4], b[4];
#define PH(buf, IH, STG) do {                                                   \
        const int kcc = lane >> 4;                                              \
        if (IH == 0) {                                                          \
            _Pragma("unroll")                                                   \
            for (int j = 0; j < 4; ++j)                                         \
                b[j] = *(const bfrag*)&lB[buf][LDSIDX(wn + j * 16 + l15, kcc)]; \
        }                                                                       \
        _Pragma("unroll")                                                       \
        for (int i = 0; i < 4; ++i)                                             \
            a[i] = *(const bfrag*)&lA[buf][LDSIDX(wm + IH * 64 + i * 16 + l15, kcc)]; \
        STG;                                                                    \
        WAITVM(8); BARRIER();                                                   \
        __builtin_amdgcn_s_setprio(1);                                          \
        _Pragma("unroll")                                                       \
        for (int i = 0; i < 4; ++i)                                             \
            _Pragma("unroll")                                                   \
            for (int j = 0; j < 4; ++j)                                         \
                acc[IH * 4 + i][j] = __builtin_amdgcn_mfma_f32_16x16x32_bf16(a[i], b[j], acc[IH * 4 + i][j], 0, 0, 0); \
        __builtin_amdgcn_s_setprio(0);                                          \
        BARRIER();                                                              \
    } while (0)

    // prologue: subtiles 0,1,2 (A+B) in flight; publish s0
    STGA(0, 0); STGB(0, 0);
    STGA(1, 1); STGB(1, 1);
    STGA(2, 2); STGB(2, 2);
    WAITVM(8);                // s0 A+B retired
    BARRIER();

#pragma unroll 1
    for (int m = 0; m < NSUB / 4; ++m) {
        const int s3 = 4 * m + 3, s4 = 4 * m + 4, s5 = 4 * m + 5, s6 = 4 * m + 6;
        PH(0, 0, STGA(3, s3));
        PH(0, 1, STGB(3, s3));
        PH(1, 0, STGA(0, s4));
        PH(1, 1, STGB(0, s4));
        PH(2, 0, STGA(1, s5));
        PH(2, 1, STGB(1, s5));
        PH(3, 0, STGA(2, s6));
        PH(3, 1, STGB(2, s6));
    }
    WAITVM(0);                // drain before LDS goes out of scope
#undef PH
#undef STGA
#undef STGB

    // epilogue: frag pairs (j, j+1) = (h1, h3) for the same 16 hidden cols
#pragma unroll
    for (int i = 0; i < 8; ++i) {
        int rbase = wm + i * 16 + ((lane >> 4) << 2);
#pragma unroll
        for (int q = 0; q < 4; ++q) {
            int rl = rbase + q;
            if (rl >= nrows) continue;
            size_t rowoff = (size_t)(m0 + rl) * HID;
#pragma unroll
            for (int jf = 0; jf < 4; jf += 2) {
                int gg = (wn >> 4) + jf;
                int col = nt * 128 + ((gg >> 1) << 4) + l15;
                float h1 = acc[i][jf][q], h3 = acc[i][jf + 1][q];
                float val = (h1 / (1.f + __expf(-h1))) * h3;
                H[rowoff + col] = f2bf(val);
            }
        }
    }
}

// ---------------- GEMM B: out[tok,:] += pw[pos] * (H[pos,:] @ w2^T) ----------------
__global__ __launch_bounds__(512, 2) void k_ffn2(const ushort* __restrict__ H,
                                                 const ushort* __restrict__ w2b,
                                                 const int* __restrict__ offs,
                                                 const int* __restrict__ perm,
                                                 const float* __restrict__ pw,
                                                 float* __restrict__ out) {
    // swizzle: the 4 nt-panels sharing one H-slice (e,mt) land on ONE XCD
    const int g = blockIdx.x;                 // 0..1023
    const int xcd = g & 7, k = g >> 3;        // k 0..127
    const int gg = xcd + ((k >> 2) << 3);     // (e,mt) group 0..255
    const int nt = k & 3;
    const int e = gg >> 5, mt = gg & 31;

    const int off = offs[e], end = offs[e + 1];
    const int m0 = off + mt * BMT;
    if (m0 >= end) return;
    const int nrows = min(BMT, end - m0);

    __shared__ ushort lA[NBUF][BMT * SK];
    __shared__ ushort lB[NBUF][BNT * SK];
    __shared__ int lTok[BMT];
    __shared__ float lPw[BMT];

    const int tid = threadIdx.x;
    if (tid < BMT) {
        bool v = tid < nrows;
        lTok[tid] = v ? perm[m0 + tid] : -1;
        lPw[tid]  = v ? pw[m0 + tid] : 0.f;
    }
    __syncthreads();

    const int lane = tid & 63, wid = tid >> 6;
    const int l15 = lane & 15;
    const int wm = (wid >> 2) * 128;
    const int wn = (wid & 3) * 64;

    ffrag acc[8][4];
#pragma unroll
    for (int i = 0; i < 8; ++i)
#pragma unroll
        for (int j = 0; j < 4; ++j) acc[i][j] = (ffrag)0.f;

    const ushort* pA[2]; const ushort* pB[2];
    {
        const size_t ebase = (size_t)e * DIM * HID;
#pragma unroll
        for (int i = 0; i < 2; ++i) {
            int s = i * 512 + tid;
            int r = SLOT_R(s), kc = SLOT_KC(s);
            int pos = m0 + r; if (pos > 2 * TK - 1) pos = 2 * TK - 1;   // clamp into H
            pA[i] = H + (size_t)pos * HID + kc * 8;
            pB[i] = w2b + ebase + (size_t)(nt * BNT + r) * HID + kc * 8;
        }
    }

    const int NSUB = HID / SK;   // 128

#define STGA(buf, sx) do { if ((sx) < NSUB) { \
        gld16(pA[0] + (sx) * SK, &lA[buf][(wid * 64) * 8]); \
        gld16(pA[1] + (sx) * SK, &lA[buf][(512 + wid * 64) * 8]); } } while (0)
#define STGB(buf, sx) do { if ((sx) < NSUB) { \
        gld16(pB[0] + (sx) * SK, &lB[buf][(wid * 64) * 8]); \
        gld16(pB[1] + (sx) * SK, &lB[buf][(512 + wid * 64) * 8]); } } while (0)

    bfrag a[4], b[4];
#define PH(buf, IH, STG) do {                                                   \
        const int kcc = lane >> 4;                                              \
        if (IH == 0) {                                                          \
            _Pragma("unroll")                                                   \
            for (int j = 0; j < 4; ++j)                                         \
                b[j] = *(const bfrag*)&lB[buf][LDSIDX(wn + j * 16 + l15, kcc)]; \
        }                                                                       \
        _Pragma("unroll")                                                       \
        for (int i = 0; i < 4; ++i)                                             \
            a[i] = *(const bfrag*)&lA[buf][LDSIDX(wm + IH * 64 + i * 16 + l15, kcc)]; \
        STG;                                                                    \
        WAITVM(8); BARRIER();                                                   \
        __builtin_amdgcn_s_setprio(1);                                          \
        _Pragma("unroll")                                                       \
        for (int i = 0; i < 4; ++i)                                             \
            _Pragma("unroll")                                                   \
            for (int j = 0; j < 4; ++j)                                         \
                acc[IH * 4 + i][j] = __builtin_amdgcn_mfma_f32_16x16x32_bf16(a[i], b[j], acc[IH * 4 + i][j], 0, 0, 0); \
        __builtin_amdgcn_s_setprio(0);                                          \
        BARRIER();                                                              \
    } while (0)

    STGA(0, 0); STGB(0, 0);
    STGA(1, 1); STGB(1, 1);
    STGA(2, 2); STGB(2, 2);
    WAITVM(8);
    BARRIER();

#pragma unroll 1
    for (int m = 0; m < NSUB / 4; ++m) {
        const int s3 = 4 * m + 3, s4 = 4 * m + 4, s5 = 4 * m + 5, s6 = 4 * m + 6;
        PH(0, 0, STGA(3, s3));
        PH(0, 1, STGB(3, s3));
        PH(1, 0, STGA(0, s4));
        PH(1, 1, STGB(0, s4));
        PH(2, 0, STGA(1, s5));
        PH(2, 1, STGB(1, s5));
        PH(3, 0, STGA(2, s6));
        PH(3, 1, STGB(2, s6));
    }
    WAITVM(0);
#undef PH
#undef STGA
#undef STGB

    const int colbase = nt * BNT + wn;
#pragma unroll
    for (int i = 0; i < 8; ++i) {
        int rbase = wm + i * 16 + ((lane >> 4) << 2);
#pragma unroll
        for (int q = 0; q < 4; ++q) {
            int rl = rbase + q;
            if (rl >= nrows) continue;
            int tok = lTok[rl];
            float w = lPw[rl];
            if (tok < 0) continue;
            size_t rowoff = (size_t)tok * DIM;
#pragma unroll
            for (int j = 0; j < 4; ++j) {
                int col = colbase + j * 16 + l15;
                atomicAdd(&out[rowoff + col], acc[i][j][q] * w);   // 2 adds/elem, deterministic
            }
        }
    }
}

extern "C" void kernel_launch(void* const* d_in, const int* in_sizes, int n_in,
                              void* d_out, int out_size, void* d_ws, size_t ws_size,
                              hipStream_t stream) {
    const float* x  = (const float*)d_in[0];
    const float* gw = (const float*)d_in[1];
    const float* w1 = (const float*)d_in[2];
    const float* w2 = (const float*)d_in[3];   // dict order: x, gate_w, w1, w2, w3 !
    const float* w3 = (const float*)d_in[4];
    float* out = (float*)d_out;

    char* ws = (char*)d_ws;
    int*    topi   = (int*)(ws + 0);
    float*  topw   = (float*)(ws + 65536);
    int*    perm   = (int*)(ws + 131072);
    float*  pw     = (float*)(ws + 196608);
    int*    counts = (int*)(ws + 262144);
    int*    offs   = (int*)(ws + 262144 + 256);
    int*    cursor = (int*)(ws + 262144 + 512);

    const size_t OFF_XB = 524288;                       // xb: 16 MiB
    const size_t OFF_H  = OFF_XB + 16777216;            // H : 128 MiB
    const size_t OFF_WA = OFF_H + 134217728;            // w1b, later w2b: 64 MiB
    const size_t OFF_WB = OFF_WA + 67108864;            // w3b: 64 MiB

    ushort* xb  = (ushort*)(ws + OFF_XB);
    ushort* H   = (ushort*)(ws + OFF_H);
    ushort* wA  = (ushort*)(ws + OFF_WA);
    ushort* wB  = (ushort*)(ws + OFF_WB);

    hipMemsetAsync(counts, 0, 32, stream);
    hipMemsetAsync(out, 0, (size_t)out_size * sizeof(float), stream);

    k_router<<<dim3(TK / 4), 256, 0, stream>>>(x, gw, topi, topw);
    k_count<<<dim3((2 * TK) / 256), 256, 0, stream>>>(topi, counts);
    k_scan<<<dim3(1), 64, 0, stream>>>(counts, offs, cursor);
    k_scatter<<<dim3(TK / 256), 256, 0, stream>>>(topi, topw, cursor, perm, pw);

    k_cvt<<<dim3((TK * DIM / 8) / 256), 256, 0, stream>>>(x, xb, TK * DIM / 8);
    k_cvt<<<dim3((NE * HID * DIM / 8) / 256), 256, 0, stream>>>(w1, wA, NE * HID * DIM / 8);
    k_cvt<<<dim3((NE * HID * DIM / 8) / 256), 256, 0, stream>>>(w3, wB, NE * HID * DIM / 8);

    k_ffn1<<<dim3(8192), 512, 0, stream>>>(xb, wA, wB, offs, perm, H);

    // w1b dead now; reuse its slot for w2b
    k_cvt<<<dim3((NE * DIM * HID / 8) / 256), 256, 0, stream>>>(w2, wA, NE * DIM * HID / 8);

    k_ffn2<<<dim3(1024), 512, 0, stream>>>(H, wA, offs, perm, pw, out);
}

// Round 7
// 1002.519 us; speedup vs baseline: 1.8346x; 1.0183x over previous
//
#include <hip/hip_runtime.h>
#include <hip/hip_bf16.h>
#include <cstdint>
#include <cstddef>

#define TK 8192
#define DIM 1024
#define HID 4096
#define NE 8

#define SK 32                  // K subtile
#define NSUB1 (DIM / SK)       // 32
#define NSUB2 (HID / SK)       // 128
#define ASZ (512 * 8)          // ushorts per A buffer (128 rows x 32)
#define BSZ (1024 * 8)         // ushorts per B buffer (256 rows x 32)

typedef __attribute__((ext_vector_type(8))) __bf16 bfrag;
typedef __attribute__((ext_vector_type(4))) float ffrag;

static __device__ __forceinline__ ushort f2bf(float f) {
    union { float f; uint32_t u; } v; v.f = f;
    uint32_t r = (v.u + 0x7fffu + ((v.u >> 16) & 1u)) >> 16;   // RNE, finite only
    return (ushort)r;
}

static __device__ __forceinline__ uint4 pack8(float4 a, float4 b) {
    union { ushort u[8]; uint4 q; } pk;
    pk.u[0] = f2bf(a.x); pk.u[1] = f2bf(a.y); pk.u[2] = f2bf(a.z); pk.u[3] = f2bf(a.w);
    pk.u[4] = f2bf(b.x); pk.u[5] = f2bf(b.y); pk.u[6] = f2bf(b.z); pk.u[7] = f2bf(b.w);
    return pk.q;
}

static __device__ __forceinline__ void gld16(const ushort* g, ushort* l) {
    __builtin_amdgcn_global_load_lds(
        (const __attribute__((address_space(1))) unsigned int*)g,
        (__attribute__((address_space(3))) unsigned int*)l, 16, 0, 0);
}

#define BARRIER() asm volatile("s_barrier" ::: "memory")
#define WAITVM(N) asm volatile("s_waitcnt vmcnt(" #N ")" ::: "memory")

// LDS subtile [R rows][32 bf16], superblocks of 8 rows x 4 chunks(16B):
// chunk (r,kc) at 16B-slot (r>>3)*32 + kc*8 + (r&7); 0 bank conflicts measured (r3-r6).
// gld16 linear slot s: r = (s>>5)*8 + (s&7), kc = (s>>3)&3.
#define LDSIDX(r, kc) ((((r) >> 3) << 8) + ((kc) << 6) + (((r) & 7) << 3))
#define SLOT_R(s)  ((((s) >> 5) << 3) | ((s) & 7))
#define SLOT_KC(s) (((s) >> 3) & 3)

// ---------------- f32 -> bf16 streaming convert ----------------
__global__ __launch_bounds__(256) void k_cvt(const float* __restrict__ src,
                                             ushort* __restrict__ dst, int n8) {
    int i = blockIdx.x * blockDim.x + threadIdx.x;
    if (i >= n8) return;
    const float4* p = (const float4*)src + (size_t)i * 2;
    ((uint4*)dst)[i] = pack8(p[0], p[1]);
}

// ---------------- router: f64-accurate logits, top-2, renormalized ----------------
__global__ __launch_bounds__(256) void k_router(const float* __restrict__ x,
                                                const float* __restrict__ gw,
                                                int* __restrict__ topi, float* __restrict__ topw) {
    int t = blockIdx.x * 4 + (threadIdx.x >> 6);
    int lane = threadIdx.x & 63;
    if (t >= TK) return;
    double acc[NE];
#pragma unroll
    for (int e = 0; e < NE; ++e) acc[e] = 0.0;
    const float* xr = x + (size_t)t * DIM;
    for (int k = lane; k < DIM; k += 64) {
        double xv = (double)xr[k];
#pragma unroll
        for (int e = 0; e < NE; ++e) acc[e] += xv * (double)gw[e * DIM + k];
    }
#pragma unroll
    for (int e = 0; e < NE; ++e) {
#pragma unroll
        for (int off = 32; off > 0; off >>= 1) acc[e] += __shfl_xor(acc[e], off);
    }
    if (lane == 0) {
        int i1 = 0;
#pragma unroll
        for (int e = 1; e < NE; ++e) if (acc[e] > acc[i1]) i1 = e;
        int i2 = (i1 == 0) ? 1 : 0;
#pragma unroll
        for (int e = 0; e < NE; ++e) if (e != i1 && acc[e] > acc[i2]) i2 = e;
        double w = 1.0 / (1.0 + exp(acc[i2] - acc[i1]));
        topi[t * 2 + 0] = i1; topi[t * 2 + 1] = i2;
        topw[t * 2 + 0] = (float)w; topw[t * 2 + 1] = (float)(1.0 - w);
    }
}

__global__ void k_count(const int* __restrict__ topi, int* __restrict__ counts) {
    int i = blockIdx.x * blockDim.x + threadIdx.x;
    if (i < 2 * TK) atomicAdd(&counts[topi[i]], 1);
}

// builds per-expert offsets AND the M=128 tile descriptor list
__global__ void k_scan(const int* __restrict__ counts, int* __restrict__ offs,
                       int* __restrict__ cursor, int* __restrict__ desc,
                       int* __restrict__ ndesc) {
    if (threadIdx.x == 0 && blockIdx.x == 0) {
        int s = 0, d = 0;
        for (int e = 0; e < NE; ++e) {
            offs[e] = s; cursor[e] = s;
            int tiles = (counts[e] + 127) >> 7;
            for (int t = 0; t < tiles; ++t) desc[d++] = (e << 16) | t;
            s += counts[e];
        }
        offs[NE] = s;
        ndesc[0] = d;
    }
}

__global__ void k_scatter(const int* __restrict__ topi, const float* __restrict__ topw,
                          int* __restrict__ cursor, int* __restrict__ perm, float* __restrict__ pw) {
    int t = blockIdx.x * blockDim.x + threadIdx.x;
    if (t >= TK) return;
#pragma unroll
    for (int k = 0; k < 2; ++k) {
        int e = topi[t * 2 + k];
        int pos = atomicAdd(&cursor[e], 1);
        perm[pos] = t; pw[pos] = topw[t * 2 + k];
    }
}

// ================= persistent GEMM cores =================
// Tile 128(M) x 256(B-rows), 8 waves (2M x 4N), per-wave 64x64 (acc 64 regs).
// NBUF=3, ONE s_barrier + ONE counted vmcnt per K=32 subtile:
//   {vmcnt(3); barrier; 8 ds_read; stage X+2 (3 gld16); setprio1; 16 MFMA; setprio0}
// Ledger: stage of X at (X-2); at (X) outstanding = X(3)+X+1(3) -> vmcnt(3)
// retires X; last subtile vmcnt(0). Single barrier is sufficient: reads are
// consumed (lgkm) before each wave's MFMA, which precedes its next barrier.

// ---------------- GEMM A (fused): H = silu(x@w1^T) * (x@w3^T) ----------------
// B rows interleave w1/w3 in 16-row groups -> (h1,h3) pairs wave-local; item
// covers 128 tokens x 128 hidden cols. items = ndesc * 32.
__global__ __launch_bounds__(512, 4) void k_ffn1(const ushort* __restrict__ xb,
                                                 const ushort* __restrict__ w1b,
                                                 const ushort* __restrict__ w3b,
                                                 const int* __restrict__ offs,
                                                 const int* __restrict__ perm,
                                                 const int* __restrict__ desc,
                                                 const int* __restrict__ ndesc_g,
                                                 ushort* __restrict__ H) {
    __shared__ ushort lA[3 * ASZ];
    __shared__ ushort lB[3 * BSZ];
    __shared__ int lTok[128];

    const int tid = threadIdx.x;
    const int lane = tid & 63, wid = tid >> 6;
    const int l15 = lane & 15, kcc = lane >> 4;
    const int wm = (wid >> 2) * 64;
    const int wn = (wid & 3) * 64;

    const int nitems = ndesc_g[0] << 5;

    const int rA = SLOT_R(tid), kcA = SLOT_KC(tid);

    bfrag a[4], b[4];
    ffrag acc[4][4];

#pragma unroll 1
    for (int w = blockIdx.x; w < nitems; w += (int)gridDim.x) {
        __syncthreads();   // prev item's readers/epilogue done before LDS reuse
        const int de = desc[w >> 5];
        const int e = de >> 16, mt = de & 0xffff, nt = w & 31;
        const int m0 = offs[e] + (mt << 7);
        const int nrows = min(128, offs[e + 1] - m0);
        if (tid < 128) lTok[tid] = (tid < nrows) ? perm[m0 + tid] : perm[m0];  // pad -> valid row, discarded
        __syncthreads();

        const ushort* pA = xb + (size_t)lTok[rA] * DIM + kcA * 8;
        const ushort* pBp[2];
        {
            const size_t ebase = (size_t)e * HID * DIM;
#pragma unroll
            for (int i2 = 0; i2 < 2; ++i2) {
                int s = i2 * 512 + tid;
                int r = SLOT_R(s), kc = SLOT_KC(s);
                int gg = r >> 4;
                int h = ((gg >> 1) << 4) | (r & 15);
                const ushort* wsrc = (gg & 1) ? w3b : w1b;
                pBp[i2] = wsrc + ebase + (size_t)(nt * 128 + h) * DIM + kc * 8;
            }
        }

#pragma unroll
        for (int i = 0; i < 4; ++i)
#pragma unroll
            for (int j = 0; j < 4; ++j) acc[i][j] = (ffrag)0.f;

#define STG1(buf, sx) do { if ((sx) < NSUB1) {                                   \
            gld16(pA + (sx) * SK, lA + (buf) * ASZ + (wid * 64) * 8);            \
            gld16(pBp[0] + (sx) * SK, lB + (buf) * BSZ + (wid * 64) * 8);        \
            gld16(pBp[1] + (sx) * SK, lB + (buf) * BSZ + (512 + wid * 64) * 8); } } while (0)

        STG1(0, 0);
        STG1(1, 1);
        int bc = 0, bs = 2;
#pragma unroll 1
        for (int X = 0; X < NSUB1 - 1; ++X) {
            WAITVM(3);
            BARRIER();
            const ushort* A_ = lA + bc * ASZ;
            const ushort* B_ = lB + bc * BSZ;
#pragma unroll
            for (int j = 0; j < 4; ++j) b[j] = *(const bfrag*)&B_[LDSIDX(wn + j * 16 + l15, kcc)];
#pragma unroll
            for (int i = 0; i < 4; ++i) a[i] = *(const bfrag*)&A_[LDSIDX(wm + i * 16 + l15, kcc)];
            STG1(bs, X + 2);
            __builtin_amdgcn_s_setprio(1);
#pragma unroll
            for (int i = 0; i < 4; ++i)
#pragma unroll
                for (int j = 0; j < 4; ++j)
                    acc[i][j] = __builtin_amdgcn_mfma_f32_16x16x32_bf16(a[i], b[j], acc[i][j], 0, 0, 0);
            __builtin_amdgcn_s_setprio(0);
            bc = (bc == 2) ? 0 : bc + 1;
            bs = (bs == 2) ? 0 : bs + 1;
        }
        {
            WAITVM(0);
            BARRIER();
            const ushort* A_ = lA + bc * ASZ;
            const ushort* B_ = lB + bc * BSZ;
#pragma unroll
            for (int j = 0; j < 4; ++j) b[j] = *(const bfrag*)&B_[LDSIDX(wn + j * 16 + l15, kcc)];
#pragma unroll
            for (int i = 0; i < 4; ++i) a[i] = *(const bfrag*)&A_[LDSIDX(wm + i * 16 + l15, kcc)];
            __builtin_amdgcn_s_setprio(1);
#pragma unroll
            for (int i = 0; i < 4; ++i)
#pragma unroll
                for (int j = 0; j < 4; ++j)
                    acc[i][j] = __builtin_amdgcn_mfma_f32_16x16x32_bf16(a[i], b[j], acc[i][j], 0, 0, 0);
            __builtin_amdgcn_s_setprio(0);
        }
#undef STG1

        // epilogue: frag pairs (j, j+1) = (h1, h3) for same 16 hidden cols
#pragma unroll
        for (int i = 0; i < 4; ++i) {
            int rbase = wm + i * 16 + ((lane >> 4) << 2);
#pragma unroll
            for (int q = 0; q < 4; ++q) {
                int rl = rbase + q;
                if (rl >= nrows) continue;
                size_t rowoff = (size_t)(m0 + rl) * HID;
#pragma unroll
                for (int jf = 0; jf < 4; jf += 2) {
                    int gg = (wn >> 4) + jf;
                    int col = nt * 128 + ((gg >> 1) << 4) + l15;
                    float h1 = acc[i][jf][q], h3 = acc[i][jf + 1][q];
                    H[rowoff + col] = f2bf((h1 / (1.f + __expf(-h1))) * h3);
                }
            }
        }
    }
}

// ---------------- GEMM B: out[tok,:] += pw[pos] * (H[pos,:] @ w2^T) ----------------
// item = (desc d, nt 0..3): 128 H-rows x 256 out cols. items = ndesc * 4.
__global__ __launch_bounds__(512, 4) void k_ffn2(const ushort* __restrict__ H,
                                                 const ushort* __restrict__ w2b,
                                                 const int* __restrict__ offs,
                                                 const int* __restrict__ perm,
                                                 const float* __restrict__ pw,
                                                 const int* __restrict__ desc,
                                                 const int* __restrict__ ndesc_g,
                                                 float* __restrict__ out) {
    __shared__ ushort lA[3 * ASZ];
    __shared__ ushort lB[3 * BSZ];
    __shared__ int lTok[128];
    __shared__ float lPw[128];

    const int tid = threadIdx.x;
    const int lane = tid & 63, wid = tid >> 6;
    const int l15 = lane & 15, kcc = lane >> 4;
    const int wm = (wid >> 2) * 64;
    const int wn = (wid & 3) * 64;

    const int nitems = ndesc_g[0] << 2;

    const int rA = SLOT_R(tid), kcA = SLOT_KC(tid);

    bfrag a[4], b[4];
    ffrag acc[4][4];

#pragma unroll 1
    for (int w = blockIdx.x; w < nitems; w += (int)gridDim.x) {
        __syncthreads();
        const int de = desc[w >> 2];
        const int e = de >> 16, mt = de & 0xffff, nt = w & 3;
        const int m0 = offs[e] + (mt << 7);
        const int nrows = min(128, offs[e + 1] - m0);
        if (tid < 128) {
            bool v = tid < nrows;
            lTok[tid] = v ? perm[m0 + tid] : 0;
            lPw[tid]  = v ? pw[m0 + tid] : 0.f;
        }
        __syncthreads();

        int posA = m0 + rA; if (posA > 2 * TK - 1) posA = 2 * TK - 1;   // clamp into H
        const ushort* pA = H + (size_t)posA * HID + kcA * 8;
        const ushort* pBp[2];
        {
            const size_t ebase = (size_t)e * DIM * HID;
#pragma unroll
            for (int i2 = 0; i2 < 2; ++i2) {
                int s = i2 * 512 + tid;
                int r = SLOT_R(s), kc = SLOT_KC(s);
                pBp[i2] = w2b + ebase + (size_t)(nt * 256 + r) * HID + kc * 8;
            }
        }

#pragma unroll
        for (int i = 0; i < 4; ++i)
#pragma unroll
            for (int j = 0; j < 4; ++j) acc[i][j] = (ffrag)0.f;

#define STG2(buf, sx) do { if ((sx) < NSUB2) {                                   \
            gld16(pA + (sx) * SK, lA + (buf) * ASZ + (wid * 64) * 8);            \
            gld16(pBp[0] + (sx) * SK, lB + (buf) * BSZ + (wid * 64) * 8);        \
            gld16(pBp[1] + (sx) * SK, lB + (buf) * BSZ + (512 + wid * 64) * 8); } } while (0)

        STG2(0, 0);
        STG2(1, 1);
        int bc = 0, bs = 2;
#pragma unroll 1
        for (int X = 0; X < NSUB2 - 1; ++X) {
            WAITVM(3);
            BARRIER();
            const ushort* A_ = lA + bc * ASZ;
            const ushort* B_ = lB + bc * BSZ;
#pragma unroll
            for (int j = 0; j < 4; ++j) b[j] = *(const bfrag*)&B_[LDSIDX(wn + j * 16 + l15, kcc)];
#pragma unroll
            for (int i = 0; i < 4; ++i) a[i] = *(const bfrag*)&A_[LDSIDX(wm + i * 16 + l15, kcc)];
            STG2(bs, X + 2);
            __builtin_amdgcn_s_setprio(1);
#pragma unroll
            for (int i = 0; i < 4; ++i)
#pragma unroll
                for (int j = 0; j < 4; ++j)
                    acc[i][j] = __builtin_amdgcn_mfma_f32_16x16x32_bf16(a[i], b[j], acc[i][j], 0, 0, 0);
            __builtin_amdgcn_s_setprio(0);
            bc = (bc == 2) ? 0 : bc + 1;
            bs = (bs == 2) ? 0 : bs + 1;
        }
        {
            WAITVM(0);
            BARRIER();
            const ushort* A_ = lA + bc * ASZ;
            const ushort* B_ = lB + bc * BSZ;
#pragma unroll
            for (int j = 0; j < 4; ++j) b[j] = *(const bfrag*)&B_[LDSIDX(wn + j * 16 + l15, kcc)];
#pragma unroll
            for (int i = 0; i < 4; ++i) a[i] = *(const bfrag*)&A_[LDSIDX(wm + i * 16 + l15, kcc)];
            __builtin_amdgcn_s_setprio(1);
#pragma unroll
            for (int i = 0; i < 4; ++i)
#pragma unroll
                for (int j = 0; j < 4; ++j)
                    acc[i][j] = __builtin_amdgcn_mfma_f32_16x16x32_bf16(a[i], b[j], acc[i][j], 0, 0, 0);
            __builtin_amdgcn_s_setprio(0);
        }
#undef STG2

#pragma unroll
        for (int i = 0; i < 4; ++i) {
            int rbase = wm + i * 16 + ((lane >> 4) << 2);
#pragma unroll
            for (int q = 0; q < 4; ++q) {
                int rl = rbase + q;
                if (rl >= nrows) continue;
                int tok = lTok[rl];
                float wgt = lPw[rl];
                size_t rowoff = (size_t)tok * DIM;
#pragma unroll
                for (int j = 0; j < 4; ++j) {
                    int col = nt * 256 + wn + j * 16 + l15;
                    atomicAdd(&out[rowoff + col], acc[i][j][q] * wgt);   // 2 adds/elem, deterministic
                }
            }
        }
    }
}

extern "C" void kernel_launch(void* const* d_in, const int* in_sizes, int n_in,
                              void* d_out, int out_size, void* d_ws, size_t ws_size,
                              hipStream_t stream) {
    const float* x  = (const float*)d_in[0];
    const float* gw = (const float*)d_in[1];
    const float* w1 = (const float*)d_in[2];
    const float* w2 = (const float*)d_in[3];   // dict order: x, gate_w, w1, w2, w3 !
    const float* w3 = (const float*)d_in[4];
    float* out = (float*)d_out;

    char* ws = (char*)d_ws;
    int*    topi   = (int*)(ws + 0);
    float*  topw   = (float*)(ws + 65536);
    int*    perm   = (int*)(ws + 131072);
    float*  pw     = (float*)(ws + 196608);
    int*    counts = (int*)(ws + 262144);
    int*    offs   = (int*)(ws + 262144 + 256);
    int*    cursor = (int*)(ws + 262144 + 512);
    int*    ndesc  = (int*)(ws + 262144 + 768);
    int*    desc   = (int*)(ws + 262144 + 1024);   // <= ~150 entries

    const size_t OFF_XB = 524288;                       // xb: 16 MiB
    const size_t OFF_H  = OFF_XB + 16777216;            // H : 128 MiB
    const size_t OFF_WA = OFF_H + 134217728;            // w1b, later w2b: 64 MiB
    const size_t OFF_WB = OFF_WA + 67108864;            // w3b: 64 MiB

    ushort* xb  = (ushort*)(ws + OFF_XB);
    ushort* H   = (ushort*)(ws + OFF_H);
    ushort* wA  = (ushort*)(ws + OFF_WA);
    ushort* wB  = (ushort*)(ws + OFF_WB);

    hipMemsetAsync(counts, 0, 32, stream);
    hipMemsetAsync(out, 0, (size_t)out_size * sizeof(float), stream);

    k_router<<<dim3(TK / 4), 256, 0, stream>>>(x, gw, topi, topw);
    k_count<<<dim3((2 * TK) / 256), 256, 0, stream>>>(topi, counts);
    k_scan<<<dim3(1), 64, 0, stream>>>(counts, offs, cursor, desc, ndesc);
    k_scatter<<<dim3(TK / 256), 256, 0, stream>>>(topi, topw, cursor, perm, pw);

    k_cvt<<<dim3((TK * DIM / 8) / 256), 256, 0, stream>>>(x, xb, TK * DIM / 8);
    k_cvt<<<dim3((NE * HID * DIM / 8) / 256), 256, 0, stream>>>(w1, wA, NE * HID * DIM / 8);
    k_cvt<<<dim3((NE * HID * DIM / 8) / 256), 256, 0, stream>>>(w3, wB, NE * HID * DIM / 8);

    k_ffn1<<<dim3(512), 512, 0, stream>>>(xb, wA, wB, offs, perm, desc, ndesc, H);

    // w1b dead now; reuse its slot for w2b
    k_cvt<<<dim3((NE * DIM * HID / 8) / 256), 256, 0, stream>>>(w2, wA, NE * DIM * HID / 8);

    k_ffn2<<<dim3(512), 512, 0, stream>>>(H, wA, offs, perm, pw, desc, ndesc, out);
}